// Round 11
// baseline (760.013 us; speedup 1.0000x reference)
//
#include <hip/hip_runtime.h>
#include <cstdint>
#include <math.h>

#define NN 50000
#define EE 800000
#define GG 64
#define NEG_SLOPE 0.2f
#define BN_EPS 1e-5f

typedef short bf16x8 __attribute__((ext_vector_type(8)));
typedef float f32x4 __attribute__((ext_vector_type(4)));

// ---------------- utility ----------------
__global__ void k_memset32(int* p, int val, int n) {
    int i = blockIdx.x * blockDim.x + threadIdx.x;
    int stride = gridDim.x * blockDim.x;
    for (; i < n; i += stride) p[i] = val;
}

__device__ inline float leaky(float x) { return x > 0.f ? x : NEG_SLOPE * x; }

__device__ inline unsigned short f2bf(float f) {
    union { float f; uint32_t u; } v;
    v.f = f;
    uint32_t u = v.u;
    return (unsigned short)((u + 0x7fffu + ((u >> 16) & 1u)) >> 16);
}

__device__ inline float bf2f(unsigned short u) {
    union { uint32_t u; float f; } v;
    v.u = (uint32_t)u << 16;
    return v.f;
}
__device__ inline float bflo(uint32_t u) { return __uint_as_float(u << 16); }
__device__ inline float bfhi(uint32_t u) { return __uint_as_float(u & 0xffff0000u); }
__device__ inline uint32_t packbf(float a, float b) {
    return (uint32_t)f2bf(a) | ((uint32_t)f2bf(b) << 16);
}

__device__ inline unsigned char f2fp8(float v) {
    int p = __builtin_amdgcn_cvt_pk_fp8_f32(v, v, 0, false);
    return (unsigned char)(p & 0xff);
}

__device__ inline void gload16(const void* g, void* l) {
    __builtin_amdgcn_global_load_lds(
        (const __attribute__((address_space(1))) unsigned int*)g,
        (__attribute__((address_space(3))) unsigned int*)l, 16, 0, 0);
}

// ---------------- one-time prep: x->bf16 convert + all W transposes ----------------
__global__ void k_prep(const float* __restrict__ x, unsigned short* __restrict__ xb,
                       const float* __restrict__ W1, const float* __restrict__ W2,
                       const float* __restrict__ W3, unsigned short* __restrict__ Wt1,
                       unsigned short* __restrict__ Wt2, unsigned short* __restrict__ Wt3) {
    int t0 = blockIdx.x * blockDim.x + threadIdx.x;
    int stride = gridDim.x * blockDim.x;
    const int n4 = NN * 512 / 4;
    for (int i = t0; i < n4; i += stride) {
        float4 v = ((const float4*)x)[i];
        uint2 o;
        o.x = packbf(v.x, v.y);
        o.y = packbf(v.z, v.w);
        ((uint2*)xb)[i] = o;
    }
    const int TR = 512 * 256 + 256 * 256 + 256 * 128;
    for (int idx = t0; idx < TR; idx += stride) {
        if (idx < 512 * 256) {
            int k = idx >> 8, m_ = idx & 255;
            Wt1[(size_t)m_ * 512 + k] = f2bf(W1[idx]);
        } else if (idx < 512 * 256 + 256 * 256) {
            int i = idx - 512 * 256;
            int k = i >> 8, m_ = i & 255;
            Wt2[(size_t)m_ * 256 + k] = f2bf(W2[i]);
        } else {
            int i = idx - (512 * 256 + 256 * 256);
            int k = i >> 7, m_ = i & 127;
            Wt3[(size_t)m_ * 256 + k] = f2bf(W3[i]);
        }
    }
}

// ---------------- MFMA GEMM (m97 structure), fp8 C, fused scores epilogue ----------------
__global__ __launch_bounds__(256) void k_gemm_mfma(
        const unsigned short* __restrict__ A, const unsigned short* __restrict__ Bt,
        unsigned char* __restrict__ C8,
        const float* __restrict__ asrc, const float* __restrict__ adst,
        float* __restrict__ es, float* __restrict__ ed,
        int NR, int K, int M, int H, int gxc) {
    __shared__ unsigned short As[2][128 * 32];
    __shared__ unsigned short Bs[2][128 * 32];
    __shared__ float esA[2][128], edA[2][128];
    int tid = threadIdx.x;
    int wave = tid >> 6, lane = tid & 63;
    int r16 = lane & 15, kg = lane >> 4;
    int wr = wave >> 1, wc = wave & 1;

    // bijective XCD swizzle (m204)
    int nwg = gridDim.x;
    int nb = blockIdx.x;
    int q = nwg >> 3, r = nwg & 7;
    int xcd = nb & 7, ii = nb >> 3;
    int w = (xcd < r ? xcd * (q + 1) : r * (q + 1) + (xcd - r) * q) + ii;
    int rowBase = (w / gxc) * 128;
    int colBase = (w % gxc) * 128;

    const unsigned short* gA[2];
    const unsigned short* gB[2];
#pragma unroll
    for (int it = 0; it < 2; ++it) {
        int j = it * 256 + tid;
        int row = j >> 2, slot = j & 3;
        int ss = slot ^ ((row >> 1) & 3);  // inverse swizzle on source
        int rg = rowBase + row;
        if (rg >= NR) rg = NR - 1;  // clamp (garbage rows never written out)
        gA[it] = A + (size_t)rg * K + ss * 8;
        gB[it] = Bt + (size_t)(colBase + row) * K + ss * 8;
    }

    auto STAGE = [&](int buf, int k0) {
#pragma unroll
        for (int it = 0; it < 2; ++it) {
            unsigned short* lbase = &As[buf][(it * 256 + wave * 64) * 8];
            gload16(gA[it] + k0, lbase);
            unsigned short* lbase2 = &Bs[buf][(it * 256 + wave * 64) * 8];
            gload16(gB[it] + k0, lbase2);
        }
    };

    f32x4 acc[4][4] = {};
    int nt = K >> 5;
    STAGE(0, 0);
    __syncthreads();
    for (int t = 0; t < nt; ++t) {
        int cur = t & 1;
        if (t + 1 < nt) STAGE(cur ^ 1, (t + 1) << 5);  // issue before compute
        bf16x8 af[4], bfr[4];
#pragma unroll
        for (int m = 0; m < 4; m++) {
            int row = wr * 64 + m * 16 + r16;
            af[m] = *(const bf16x8*)&As[cur][row * 32 + (kg ^ ((row >> 1) & 3)) * 8];
        }
#pragma unroll
        for (int n = 0; n < 4; n++) {
            int row = wc * 64 + n * 16 + r16;
            bfr[n] = *(const bf16x8*)&Bs[cur][row * 32 + (kg ^ ((row >> 1) & 3)) * 8];
        }
#pragma unroll
        for (int m = 0; m < 4; m++)
#pragma unroll
            for (int n = 0; n < 4; n++)
                acc[m][n] = __builtin_amdgcn_mfma_f32_16x16x32_bf16(af[m], bfr[n], acc[m][n], 0, 0, 0);
        __syncthreads();
    }
    // ---- C write (fp8 e4m3) ----
    int crow0 = rowBase + wr * 64;
    int ccol = colBase + wc * 64 + r16;
#pragma unroll
    for (int m = 0; m < 4; m++) {
#pragma unroll
        for (int j = 0; j < 4; j++) {
            int row = crow0 + m * 16 + kg * 4 + j;
            if (row < NR) {
#pragma unroll
                for (int n = 0; n < 4; n++)
                    C8[(size_t)row * M + ccol + n * 16] = f2fp8(acc[m][n][j]);
            }
        }
    }
    // ---- fused attention-score epilogue (f32 acc, full precision) ----
    int h_blk = colBase >> 7;
    float as_[4], ad_[4];
#pragma unroll
    for (int n = 0; n < 4; n++) {
        int ch = wc * 64 + n * 16 + r16;
        as_[n] = asrc[h_blk * 128 + ch];
        ad_[n] = adst[h_blk * 128 + ch];
    }
#pragma unroll
    for (int m = 0; m < 4; m++) {
#pragma unroll
        for (int j = 0; j < 4; j++) {
            float e1 = 0.f, e2 = 0.f;
#pragma unroll
            for (int n = 0; n < 4; n++) {
                e1 += acc[m][n][j] * as_[n];
                e2 += acc[m][n][j] * ad_[n];
            }
#pragma unroll
            for (int mask = 1; mask < 16; mask <<= 1) {
                e1 += __shfl_xor(e1, mask, 64);
                e2 += __shfl_xor(e2, mask, 64);
            }
            if (r16 == 0) {
                int lr = wr * 64 + m * 16 + kg * 4 + j;
                esA[wc][lr] = e1;
                edA[wc][lr] = e2;
            }
        }
    }
    __syncthreads();
    if (tid < 128) {
        int row = rowBase + tid;
        if (row < NR) {
            es[row * H + h_blk] = esA[0][tid] + esA[1][tid];
            ed[row * H + h_blk] = edA[0][tid] + edA[1][tid];
        }
    }
}

// ---------------- fused softmax + aggregation (no-max form, fp8 gather) ----------------
template <int VEC>
__device__ inline void edge_load(const unsigned char* rp, uint2& w) {
    if constexpr (VEC == 8) {
        w = *(const uint2*)rp;
    } else {
        w.x = *(const unsigned int*)rp;
        w.y = 0;
    }
}

template <int VEC>
__device__ inline void edge_acc(float* acc, float e, const uint2& w) {
    auto p0 = __builtin_amdgcn_cvt_pk_f32_fp8(w.x, false);
    auto p1 = __builtin_amdgcn_cvt_pk_f32_fp8(w.x, true);
    acc[0] += e * p0[0]; acc[1] += e * p0[1];
    acc[2] += e * p1[0]; acc[3] += e * p1[1];
    if constexpr (VEC == 8) {
        auto p2 = __builtin_amdgcn_cvt_pk_f32_fp8(w.y, false);
        auto p3 = __builtin_amdgcn_cvt_pk_f32_fp8(w.y, true);
        acc[4] += e * p2[0]; acc[5] += e * p2[1];
        acc[6] += e * p3[0]; acc[7] += e * p3[1];
    }
}

// POOL=true: skip hbuf store; atomically accumulate f32 result into pooled[batch[n]]
template <int VEC, int H, bool POOL>
__global__ __launch_bounds__(256) void k_aggregate(
        const unsigned char* __restrict__ xl, const float* __restrict__ es,
        const float* __restrict__ ed, const int* __restrict__ offsets,
        const int* __restrict__ count, const int* __restrict__ ssrc,
        const float* __restrict__ bias, unsigned short* __restrict__ out,
        const int* __restrict__ batch, float* __restrict__ pooled, int* __restrict__ cnt) {
    const int M = 32 * VEC;
    int wid = threadIdx.x >> 6;
    int n = blockIdx.x * 4 + wid;
    if (n >= NN) return;
    int lane = threadIdx.x & 63;
    int half = lane >> 5, l32 = lane & 31;
    int c0 = l32 * VEC;
    int h = (H == 2) ? (c0 >> 7) : 0;

    float edn0, edn1 = 0.f, self0, self1 = 0.f;
    if constexpr (H == 2) {
        float2 edp = *(const float2*)&ed[n * 2];
        float2 esp = *(const float2*)&es[n * 2];
        edn0 = edp.x; edn1 = edp.y;
        self0 = __expf(leaky(esp.x + edn0));
        self1 = __expf(leaky(esp.y + edn1));
    } else {
        edn0 = ed[n];
        self0 = __expf(leaky(es[n] + edn0));
    }
    float ex_self = (H == 2 && h == 1) ? self1 : self0;

    float acc[VEC] = {};
    if (half == 0) {
        uint2 w;
        edge_load<VEC>(xl + (size_t)n * M + c0, w);
        edge_acc<VEC>(acc, ex_self, w);
    }

    // ---- single pass: cooperative score -> wave LDS, half-wave gather ----
    __shared__ int ls[4][64];
    __shared__ float le[4][H][64];
    float den0 = 0.f, den1 = 0.f;
    int s0 = offsets[n], cnte = count[n];
    for (int base = 0; base < cnte; base += 64) {
        int i = base + lane;
        int s = 0;
        float e0 = 0.f, e1 = 0.f;
        if (i < cnte) {
            s = ssrc[s0 + i];
            if constexpr (H == 2) {
                float2 esp = *(const float2*)&es[s * 2];
                e0 = __expf(leaky(esp.x + edn0)); den0 += e0;
                e1 = __expf(leaky(esp.y + edn1)); den1 += e1;
            } else {
                e0 = __expf(leaky(es[s] + edn0)); den0 += e0;
            }
        }
        ls[wid][lane] = s;
        le[wid][0][lane] = e0;
        if constexpr (H == 2) le[wid][1][lane] = e1;
        asm volatile("s_waitcnt lgkmcnt(0)" ::: "memory");
        int lim = min(64, cnte - base);
        int j = half;
        for (; j + 7 < lim; j += 8) {  // 4 independent edges in flight
            int sA = ls[wid][j], sB = ls[wid][j + 2], sC = ls[wid][j + 4], sD = ls[wid][j + 6];
            float eA = le[wid][h][j], eB = le[wid][h][j + 2];
            float eC = le[wid][h][j + 4], eD = le[wid][h][j + 6];
            uint2 wA, wB, wC, wD;
            edge_load<VEC>(xl + (size_t)sA * M + c0, wA);
            edge_load<VEC>(xl + (size_t)sB * M + c0, wB);
            edge_load<VEC>(xl + (size_t)sC * M + c0, wC);
            edge_load<VEC>(xl + (size_t)sD * M + c0, wD);
            edge_acc<VEC>(acc, eA, wA);
            edge_acc<VEC>(acc, eB, wB);
            edge_acc<VEC>(acc, eC, wC);
            edge_acc<VEC>(acc, eD, wD);
        }
        for (; j < lim; j += 2) {
            int sA = ls[wid][j];
            float eA = le[wid][h][j];
            uint2 wA;
            edge_load<VEC>(xl + (size_t)sA * M + c0, wA);
            edge_acc<VEC>(acc, eA, wA);
        }
    }

    // ---- reductions ----
#pragma unroll
    for (int off = 32; off > 0; off >>= 1) {
        den0 += __shfl_xor(den0, off, 64);
        if constexpr (H == 2) den1 += __shfl_xor(den1, off, 64);
    }
#pragma unroll
    for (int v = 0; v < VEC; v++) acc[v] += __shfl_xor(acc[v], 32, 64);

    float den = ((H == 2 && h == 1) ? den1 : den0) + ex_self + 1e-16f;
    float inv = 1.f / den;
    if (half == 0) {
        if constexpr (POOL) {
            int g = batch[n];
            if (lane == 0) atomicAdd(&cnt[g], 1);
#pragma unroll
            for (int v = 0; v < VEC; v++)
                atomicAdd(&pooled[g * 128 + c0 + v], acc[v] * inv + bias[c0 + v]);
        } else {
            unsigned short* op = out + (size_t)n * M + c0;
            if constexpr (VEC == 8) {
                uint4 o;
                o.x = packbf(acc[0] * inv + bias[c0 + 0], acc[1] * inv + bias[c0 + 1]);
                o.y = packbf(acc[2] * inv + bias[c0 + 2], acc[3] * inv + bias[c0 + 3]);
                o.z = packbf(acc[4] * inv + bias[c0 + 4], acc[5] * inv + bias[c0 + 5]);
                o.w = packbf(acc[6] * inv + bias[c0 + 6], acc[7] * inv + bias[c0 + 7]);
                *(uint4*)op = o;
            } else {
                uint2 o;
                o.x = packbf(acc[0] * inv + bias[c0 + 0], acc[1] * inv + bias[c0 + 1]);
                o.y = packbf(acc[2] * inv + bias[c0 + 2], acc[3] * inv + bias[c0 + 3]);
                *(uint2*)op = o;
            }
        }
    }
}

// ---------------- edge sort by dst (counting sort) ----------------
__global__ void k_count(const int* __restrict__ dst, int* __restrict__ count) {
    int e = blockIdx.x * blockDim.x + threadIdx.x;
    if (e < EE) atomicAdd(&count[dst[e]], 1);
}

// single-block exclusive scan (1024 threads, wave-shuffle + carry)
__global__ __launch_bounds__(1024) void k_scan(const int* __restrict__ in,
                                               int* __restrict__ out, int n) {
    __shared__ int wsum[16];
    int tid = threadIdx.x;
    int wid = tid >> 6, lane = tid & 63;
    int carry = 0;
    for (int base = 0; base < n; base += 1024) {
        int i = base + tid;
        int v = (i < n) ? in[i] : 0;
        int x = v;
#pragma unroll
        for (int off = 1; off < 64; off <<= 1) {
            int y = __shfl_up(x, off, 64);
            if (lane >= off) x += y;
        }
        if (lane == 63) wsum[wid] = x;
        __syncthreads();
        if (wid == 0) {
            int t = (lane < 16) ? wsum[lane] : 0;
#pragma unroll
            for (int off = 1; off < 16; off <<= 1) {
                int y = __shfl_up(t, off, 64);
                if (lane >= off) t += y;
            }
            if (lane < 16) wsum[lane] = t;
        }
        __syncthreads();
        int woff = (wid > 0) ? wsum[wid - 1] : 0;
        if (i < n) out[i] = carry + woff + x - v;
        carry += wsum[15];
        __syncthreads();
    }
}

__global__ void k_scatter(const int* __restrict__ src, const int* __restrict__ dst,
                          const int* __restrict__ offsets, int* __restrict__ cursor,
                          int* __restrict__ ssrc) {
    int e = blockIdx.x * blockDim.x + threadIdx.x;
    if (e >= EE) return;
    int d = dst[e];
    int p = offsets[d] + atomicAdd(&cursor[d], 1);
    ssrc[p] = src[e];
}

// ---------------- batch norm: 256-block partial stats (f32, no atomics) ----------------
__global__ __launch_bounds__(256) void k_bn_stats(const unsigned short* __restrict__ h,
                                                  float* __restrict__ part) {
    int tid = threadIdx.x;
    int bid = blockIdx.x;      // 256 blocks
    int c0 = (tid & 31) * 8;   // 8 cols per thread
    int rg = tid >> 5;         // 8 row groups
    float s[8] = {}, s2[8] = {};
    for (int r = bid * 8 + rg; r < NN; r += 2048) {
        uint4 v = *(const uint4*)(h + (size_t)r * 256 + c0);
        float f;
        f = bflo(v.x); s[0] += f; s2[0] += f * f;
        f = bfhi(v.x); s[1] += f; s2[1] += f * f;
        f = bflo(v.y); s[2] += f; s2[2] += f * f;
        f = bfhi(v.y); s[3] += f; s2[3] += f * f;
        f = bflo(v.z); s[4] += f; s2[4] += f * f;
        f = bfhi(v.z); s[5] += f; s2[5] += f * f;
        f = bflo(v.w); s[6] += f; s2[6] += f * f;
        f = bfhi(v.w); s[7] += f; s2[7] += f * f;
    }
    __shared__ float sb[8][256];
#pragma unroll
    for (int v = 0; v < 8; v++) sb[rg][c0 + v] = s[v];
    __syncthreads();
    float tot = 0.f;
#pragma unroll
    for (int g = 0; g < 8; g++) tot += sb[g][tid];
    part[bid * 512 + tid] = tot;
    __syncthreads();
#pragma unroll
    for (int v = 0; v < 8; v++) sb[rg][c0 + v] = s2[v];
    __syncthreads();
    tot = 0.f;
#pragma unroll
    for (int g = 0; g < 8; g++) tot += sb[g][tid];
    part[bid * 512 + 256 + tid] = tot;
}

__global__ void k_bn_finalize(const float* __restrict__ part, const float* __restrict__ g,
                              const float* __restrict__ be, float* __restrict__ scale,
                              float* __restrict__ shift) {
    int t = threadIdx.x;  // 256
    float s = 0.f, s2 = 0.f;
    for (int b = 0; b < 256; b++) {
        s += part[b * 512 + t];
        s2 += part[b * 512 + 256 + t];
    }
    float mu = s / (float)NN;
    float var = s2 / (float)NN - mu * mu;
    float sc = g[t] * rsqrtf(var + BN_EPS);
    scale[t] = sc;
    shift[t] = be[t] - mu * sc;
}

__global__ void k_bn_apply(unsigned short* __restrict__ h, const float* __restrict__ scale,
                           const float* __restrict__ shift) {
    int i = blockIdx.x * blockDim.x + threadIdx.x;
    int stride = gridDim.x * blockDim.x;
    int total = NN * 256 / 8;
    uint4* h4 = (uint4*)h;
    for (; i < total; i += stride) {
        uint4 v = h4[i];
        int t = (i * 8) & 255;
        float f0 = fmaxf(bflo(v.x) * scale[t + 0] + shift[t + 0], 0.f);
        float f1 = fmaxf(bfhi(v.x) * scale[t + 1] + shift[t + 1], 0.f);
        float f2 = fmaxf(bflo(v.y) * scale[t + 2] + shift[t + 2], 0.f);
        float f3 = fmaxf(bfhi(v.y) * scale[t + 3] + shift[t + 3], 0.f);
        float f4 = fmaxf(bflo(v.z) * scale[t + 4] + shift[t + 4], 0.f);
        float f5 = fmaxf(bfhi(v.z) * scale[t + 5] + shift[t + 5], 0.f);
        float f6 = fmaxf(bflo(v.w) * scale[t + 6] + shift[t + 6], 0.f);
        float f7 = fmaxf(bfhi(v.w) * scale[t + 7] + shift[t + 7], 0.f);
        v.x = packbf(f0, f1);
        v.y = packbf(f2, f3);
        v.z = packbf(f4, f5);
        v.w = packbf(f6, f7);
        h4[i] = v;
    }
}

// ---------------- final linear ----------------
__global__ void k_final(const float* __restrict__ pooled, const int* __restrict__ cnt,
                        const float* __restrict__ Wlin, const float* __restrict__ blin,
                        float* __restrict__ out) {
    int g = blockIdx.x;   // 64
    int o = threadIdx.x;  // 64
    float c = (float)max(cnt[g], 1);
    float acc = 0.f;
    for (int k = 0; k < 128; k++) acc += pooled[g * 128 + k] * Wlin[k * 64 + o];
    out[g * 64 + o] = acc / c + blin[o];
}

// ---------------- host ----------------
extern "C" void kernel_launch(void* const* d_in, const int* in_sizes, int n_in,
                              void* d_out, int out_size, void* d_ws, size_t ws_size,
                              hipStream_t stream) {
    const float* x = (const float*)d_in[0];
    const int* ei = (const int*)d_in[1];
    const int* batch = (const int*)d_in[2];
    const float* W1 = (const float*)d_in[3];
    const float* as1 = (const float*)d_in[4];
    const float* ad1 = (const float*)d_in[5];
    const float* b1 = (const float*)d_in[6];
    const float* g1 = (const float*)d_in[7];
    const float* be1 = (const float*)d_in[8];
    const float* W2 = (const float*)d_in[9];
    const float* as2 = (const float*)d_in[10];
    const float* ad2 = (const float*)d_in[11];
    const float* b2 = (const float*)d_in[12];
    const float* g2 = (const float*)d_in[13];
    const float* be2 = (const float*)d_in[14];
    const float* W3 = (const float*)d_in[15];
    const float* as3 = (const float*)d_in[16];
    const float* ad3 = (const float*)d_in[17];
    const float* b3 = (const float*)d_in[18];
    const float* Wlin = (const float*)d_in[19];
    const float* blin = (const float*)d_in[20];
    float* out = (float*)d_out;

    const int* src = ei;
    const int* dst = ei + EE;

    char* ws = (char*)d_ws;
    size_t off = 0;
    auto alloc = [&](size_t bytes) -> void* {
        void* p = (void*)(ws + off);
        off = (off + bytes + 255) & ~(size_t)255;
        return p;
    };
    unsigned short* xb = (unsigned short*)alloc((size_t)NN * 512 * 2);
    unsigned char* xl = (unsigned char*)alloc((size_t)NN * 256);
    unsigned short* hbuf = (unsigned short*)alloc((size_t)NN * 256 * 2);
    unsigned short* Wt1 = (unsigned short*)alloc((size_t)256 * 512 * 2);
    unsigned short* Wt2 = (unsigned short*)alloc((size_t)256 * 256 * 2);
    unsigned short* Wt3 = (unsigned short*)alloc((size_t)128 * 256 * 2);
    float* es = (float*)alloc((size_t)NN * 2 * 4);
    float* ed = (float*)alloc((size_t)NN * 2 * 4);
    int* cc = (int*)alloc((size_t)2 * NN * 4);  // count | cursor (one memset)
    int* count = cc;
    int* cursor = cc + NN;
    int* offsets = (int*)alloc((size_t)NN * 4);
    int* ssrc = (int*)alloc((size_t)EE * 4);
    float* bnpart = (float*)alloc((size_t)256 * 512 * 4);
    float* bnscale = (float*)alloc(256 * 4);
    float* bnshift = (float*)alloc(256 * 4);
    float* pooled = (float*)alloc(64 * 128 * 4);  // cnt directly follows (aligned)
    int* cnt = (int*)alloc(64 * 4);

    const int EB = (EE + 255) / 256;  // 3125
    const int AGB = (NN + 3) / 4;     // 12500
    const int NRB = (NN + 127) / 128; // 391

    // ---- one-time input prep (convert + transposes fused) ----
    k_prep<<<2048, 256, 0, stream>>>(x, xb, W1, W2, W3, Wt1, Wt2, Wt3);

    // ---- sort edges by dst (once; graph shared across layers) ----
    k_memset32<<<128, 256, 0, stream>>>(cc, 0, 2 * NN);
    k_count<<<EB, 256, 0, stream>>>(dst, count);
    k_scan<<<1, 1024, 0, stream>>>(count, offsets, NN);
    k_scatter<<<EB, 256, 0, stream>>>(src, dst, offsets, cursor, ssrc);

    auto bn_relu = [&](unsigned short* h, const float* g_, const float* be_) {
        k_bn_stats<<<256, 256, 0, stream>>>(h, bnpart);
        k_bn_finalize<<<1, 256, 0, stream>>>(bnpart, g_, be_, bnscale, bnshift);
        k_bn_apply<<<1024, 256, 0, stream>>>(h, bnscale, bnshift);
    };

    // ---- layer 1: 512 -> [2,128] concat 256 ----
    k_gemm_mfma<<<2 * NRB, 256, 0, stream>>>(xb, Wt1, xl, as1, ad1, es, ed, NN, 512, 256, 2, 2);
    k_aggregate<8, 2, false><<<AGB, 256, 0, stream>>>(xl, es, ed, offsets, count, ssrc, b1,
                                                      hbuf, nullptr, nullptr, nullptr);
    bn_relu(hbuf, g1, be1);

    // ---- layer 2: 256 -> 256 ----
    k_gemm_mfma<<<2 * NRB, 256, 0, stream>>>(hbuf, Wt2, xl, as2, ad2, es, ed, NN, 256, 256, 2, 2);
    k_aggregate<8, 2, false><<<AGB, 256, 0, stream>>>(xl, es, ed, offsets, count, ssrc, b2,
                                                      hbuf, nullptr, nullptr, nullptr);
    bn_relu(hbuf, g2, be2);

    // ---- layer 3: 256 -> 128, 1 head; pool fused into aggregate ----
    k_memset32<<<33, 256, 0, stream>>>((int*)pooled, 0, 64 * 128 + 64);  // pooled + cnt
    k_gemm_mfma<<<NRB, 256, 0, stream>>>(hbuf, Wt3, xl, as3, ad3, es, ed, NN, 256, 128, 1, 1);
    k_aggregate<4, 1, true><<<AGB, 256, 0, stream>>>(xl, es, ed, offsets, count, ssrc, b3,
                                                     nullptr, batch, pooled, cnt);

    // ---- final linear ----
    k_final<<<GG, 64, 0, stream>>>(pooled, cnt, Wlin, blin, out);
}

// Round 12
// 468.931 us; speedup vs baseline: 1.6207x; 1.6207x over previous
//
#include <hip/hip_runtime.h>
#include <cstdint>
#include <math.h>

#define NN 50000
#define EE 800000
#define GG 64
#define NEG_SLOPE 0.2f
#define BN_EPS 1e-5f

typedef short bf16x8 __attribute__((ext_vector_type(8)));
typedef float f32x4 __attribute__((ext_vector_type(4)));

// ---------------- utility ----------------
__global__ void k_memset32(int* p, int val, int n) {
    int i = blockIdx.x * blockDim.x + threadIdx.x;
    int stride = gridDim.x * blockDim.x;
    for (; i < n; i += stride) p[i] = val;
}

__device__ inline float leaky(float x) { return x > 0.f ? x : NEG_SLOPE * x; }

__device__ inline unsigned short f2bf(float f) {
    union { float f; uint32_t u; } v;
    v.f = f;
    uint32_t u = v.u;
    return (unsigned short)((u + 0x7fffu + ((u >> 16) & 1u)) >> 16);
}

__device__ inline float bf2f(unsigned short u) {
    union { uint32_t u; float f; } v;
    v.u = (uint32_t)u << 16;
    return v.f;
}
__device__ inline float bflo(uint32_t u) { return __uint_as_float(u << 16); }
__device__ inline float bfhi(uint32_t u) { return __uint_as_float(u & 0xffff0000u); }
__device__ inline uint32_t packbf(float a, float b) {
    return (uint32_t)f2bf(a) | ((uint32_t)f2bf(b) << 16);
}

__device__ inline unsigned char f2fp8(float v) {
    int p = __builtin_amdgcn_cvt_pk_fp8_f32(v, v, 0, false);
    return (unsigned char)(p & 0xff);
}

__device__ inline void gload16(const void* g, void* l) {
    __builtin_amdgcn_global_load_lds(
        (const __attribute__((address_space(1))) unsigned int*)g,
        (__attribute__((address_space(3))) unsigned int*)l, 16, 0, 0);
}

// ---------------- one-time prep: x->bf16 convert + all W transposes ----------------
__global__ void k_prep(const float* __restrict__ x, unsigned short* __restrict__ xb,
                       const float* __restrict__ W1, const float* __restrict__ W2,
                       const float* __restrict__ W3, unsigned short* __restrict__ Wt1,
                       unsigned short* __restrict__ Wt2, unsigned short* __restrict__ Wt3) {
    int t0 = blockIdx.x * blockDim.x + threadIdx.x;
    int stride = gridDim.x * blockDim.x;
    const int n4 = NN * 512 / 4;
    for (int i = t0; i < n4; i += stride) {
        float4 v = ((const float4*)x)[i];
        uint2 o;
        o.x = packbf(v.x, v.y);
        o.y = packbf(v.z, v.w);
        ((uint2*)xb)[i] = o;
    }
    const int TR = 512 * 256 + 256 * 256 + 256 * 128;
    for (int idx = t0; idx < TR; idx += stride) {
        if (idx < 512 * 256) {
            int k = idx >> 8, m_ = idx & 255;
            Wt1[(size_t)m_ * 512 + k] = f2bf(W1[idx]);
        } else if (idx < 512 * 256 + 256 * 256) {
            int i = idx - 512 * 256;
            int k = i >> 8, m_ = i & 255;
            Wt2[(size_t)m_ * 256 + k] = f2bf(W2[i]);
        } else {
            int i = idx - (512 * 256 + 256 * 256);
            int k = i >> 7, m_ = i & 127;
            Wt3[(size_t)m_ * 256 + k] = f2bf(W3[i]);
        }
    }
}

// ---------------- MFMA GEMM (m97 structure), fp8 C, fused scores epilogue ----------------
__global__ __launch_bounds__(256) void k_gemm_mfma(
        const unsigned short* __restrict__ A, const unsigned short* __restrict__ Bt,
        unsigned char* __restrict__ C8,
        const float* __restrict__ asrc, const float* __restrict__ adst,
        float* __restrict__ es, float* __restrict__ ed,
        int NR, int K, int M, int H, int gxc) {
    __shared__ unsigned short As[2][128 * 32];
    __shared__ unsigned short Bs[2][128 * 32];
    __shared__ float esA[2][128], edA[2][128];
    int tid = threadIdx.x;
    int wave = tid >> 6, lane = tid & 63;
    int r16 = lane & 15, kg = lane >> 4;
    int wr = wave >> 1, wc = wave & 1;

    // bijective XCD swizzle (m204)
    int nwg = gridDim.x;
    int nb = blockIdx.x;
    int q = nwg >> 3, r = nwg & 7;
    int xcd = nb & 7, ii = nb >> 3;
    int w = (xcd < r ? xcd * (q + 1) : r * (q + 1) + (xcd - r) * q) + ii;
    int rowBase = (w / gxc) * 128;
    int colBase = (w % gxc) * 128;

    const unsigned short* gA[2];
    const unsigned short* gB[2];
#pragma unroll
    for (int it = 0; it < 2; ++it) {
        int j = it * 256 + tid;
        int row = j >> 2, slot = j & 3;
        int ss = slot ^ ((row >> 1) & 3);  // inverse swizzle on source
        int rg = rowBase + row;
        if (rg >= NR) rg = NR - 1;  // clamp (garbage rows never written out)
        gA[it] = A + (size_t)rg * K + ss * 8;
        gB[it] = Bt + (size_t)(colBase + row) * K + ss * 8;
    }

    auto STAGE = [&](int buf, int k0) {
#pragma unroll
        for (int it = 0; it < 2; ++it) {
            unsigned short* lbase = &As[buf][(it * 256 + wave * 64) * 8];
            gload16(gA[it] + k0, lbase);
            unsigned short* lbase2 = &Bs[buf][(it * 256 + wave * 64) * 8];
            gload16(gB[it] + k0, lbase2);
        }
    };

    f32x4 acc[4][4] = {};
    int nt = K >> 5;
    STAGE(0, 0);
    __syncthreads();
    for (int t = 0; t < nt; ++t) {
        int cur = t & 1;
        if (t + 1 < nt) STAGE(cur ^ 1, (t + 1) << 5);  // issue before compute
        bf16x8 af[4], bfr[4];
#pragma unroll
        for (int m = 0; m < 4; m++) {
            int row = wr * 64 + m * 16 + r16;
            af[m] = *(const bf16x8*)&As[cur][row * 32 + (kg ^ ((row >> 1) & 3)) * 8];
        }
#pragma unroll
        for (int n = 0; n < 4; n++) {
            int row = wc * 64 + n * 16 + r16;
            bfr[n] = *(const bf16x8*)&Bs[cur][row * 32 + (kg ^ ((row >> 1) & 3)) * 8];
        }
#pragma unroll
        for (int m = 0; m < 4; m++)
#pragma unroll
            for (int n = 0; n < 4; n++)
                acc[m][n] = __builtin_amdgcn_mfma_f32_16x16x32_bf16(af[m], bfr[n], acc[m][n], 0, 0, 0);
        __syncthreads();
    }
    // ---- C write (fp8 e4m3) ----
    int crow0 = rowBase + wr * 64;
    int ccol = colBase + wc * 64 + r16;
#pragma unroll
    for (int m = 0; m < 4; m++) {
#pragma unroll
        for (int j = 0; j < 4; j++) {
            int row = crow0 + m * 16 + kg * 4 + j;
            if (row < NR) {
#pragma unroll
                for (int n = 0; n < 4; n++)
                    C8[(size_t)row * M + ccol + n * 16] = f2fp8(acc[m][n][j]);
            }
        }
    }
    // ---- fused attention-score epilogue (f32 acc, full precision) ----
    int h_blk = colBase >> 7;
    float as_[4], ad_[4];
#pragma unroll
    for (int n = 0; n < 4; n++) {
        int ch = wc * 64 + n * 16 + r16;
        as_[n] = asrc[h_blk * 128 + ch];
        ad_[n] = adst[h_blk * 128 + ch];
    }
#pragma unroll
    for (int m = 0; m < 4; m++) {
#pragma unroll
        for (int j = 0; j < 4; j++) {
            float e1 = 0.f, e2 = 0.f;
#pragma unroll
            for (int n = 0; n < 4; n++) {
                e1 += acc[m][n][j] * as_[n];
                e2 += acc[m][n][j] * ad_[n];
            }
#pragma unroll
            for (int mask = 1; mask < 16; mask <<= 1) {
                e1 += __shfl_xor(e1, mask, 64);
                e2 += __shfl_xor(e2, mask, 64);
            }
            if (r16 == 0) {
                int lr = wr * 64 + m * 16 + kg * 4 + j;
                esA[wc][lr] = e1;
                edA[wc][lr] = e2;
            }
        }
    }
    __syncthreads();
    if (tid < 128) {
        int row = rowBase + tid;
        if (row < NR) {
            es[row * H + h_blk] = esA[0][tid] + esA[1][tid];
            ed[row * H + h_blk] = edA[0][tid] + edA[1][tid];
        }
    }
}

// ---------------- fused softmax + aggregation (no-max form, fp8 gather) ----------------
template <int VEC>
__device__ inline void edge_load(const unsigned char* rp, uint2& w) {
    if constexpr (VEC == 8) {
        w = *(const uint2*)rp;
    } else {
        w.x = *(const unsigned int*)rp;
        w.y = 0;
    }
}

template <int VEC>
__device__ inline void edge_acc(float* acc, float e, const uint2& w) {
    auto p0 = __builtin_amdgcn_cvt_pk_f32_fp8(w.x, false);
    auto p1 = __builtin_amdgcn_cvt_pk_f32_fp8(w.x, true);
    acc[0] += e * p0[0]; acc[1] += e * p0[1];
    acc[2] += e * p1[0]; acc[3] += e * p1[1];
    if constexpr (VEC == 8) {
        auto p2 = __builtin_amdgcn_cvt_pk_f32_fp8(w.y, false);
        auto p3 = __builtin_amdgcn_cvt_pk_f32_fp8(w.y, true);
        acc[4] += e * p2[0]; acc[5] += e * p2[1];
        acc[6] += e * p3[0]; acc[7] += e * p3[1];
    }
}

template <int VEC, int H>  // M = 32*VEC cols; lanes 0-31 even edges, 32-63 odd edges
__global__ __launch_bounds__(256) void k_aggregate(
        const unsigned char* __restrict__ xl, const float* __restrict__ es,
        const float* __restrict__ ed, const int* __restrict__ offsets,
        const int* __restrict__ count, const int* __restrict__ ssrc,
        const float* __restrict__ bias, unsigned short* __restrict__ out) {
    const int M = 32 * VEC;
    int wid = threadIdx.x >> 6;
    int n = blockIdx.x * 4 + wid;
    if (n >= NN) return;
    int lane = threadIdx.x & 63;
    int half = lane >> 5, l32 = lane & 31;
    int c0 = l32 * VEC;
    int h = (H == 2) ? (c0 >> 7) : 0;

    float edn0, edn1 = 0.f, self0, self1 = 0.f;
    if constexpr (H == 2) {
        float2 edp = *(const float2*)&ed[n * 2];
        float2 esp = *(const float2*)&es[n * 2];
        edn0 = edp.x; edn1 = edp.y;
        self0 = __expf(leaky(esp.x + edn0));
        self1 = __expf(leaky(esp.y + edn1));
    } else {
        edn0 = ed[n];
        self0 = __expf(leaky(es[n] + edn0));
    }
    float ex_self = (H == 2 && h == 1) ? self1 : self0;

    float acc[VEC] = {};
    if (half == 0) {
        uint2 w;
        edge_load<VEC>(xl + (size_t)n * M + c0, w);
        edge_acc<VEC>(acc, ex_self, w);
    }

    // ---- single pass: cooperative score -> wave LDS, half-wave gather ----
    __shared__ int ls[4][64];
    __shared__ float le[4][H][64];
    float den0 = 0.f, den1 = 0.f;
    int s0 = offsets[n], cnte = count[n];
    for (int base = 0; base < cnte; base += 64) {
        int i = base + lane;
        int s = 0;
        float e0 = 0.f, e1 = 0.f;
        if (i < cnte) {
            s = ssrc[s0 + i];
            if constexpr (H == 2) {
                float2 esp = *(const float2*)&es[s * 2];
                e0 = __expf(leaky(esp.x + edn0)); den0 += e0;
                e1 = __expf(leaky(esp.y + edn1)); den1 += e1;
            } else {
                e0 = __expf(leaky(es[s] + edn0)); den0 += e0;
            }
        }
        ls[wid][lane] = s;
        le[wid][0][lane] = e0;
        if constexpr (H == 2) le[wid][1][lane] = e1;
        asm volatile("s_waitcnt lgkmcnt(0)" ::: "memory");
        int lim = min(64, cnte - base);
        int j = half;
        for (; j + 7 < lim; j += 8) {  // 4 independent edges in flight
            int sA = ls[wid][j], sB = ls[wid][j + 2], sC = ls[wid][j + 4], sD = ls[wid][j + 6];
            float eA = le[wid][h][j], eB = le[wid][h][j + 2];
            float eC = le[wid][h][j + 4], eD = le[wid][h][j + 6];
            uint2 wA, wB, wC, wD;
            edge_load<VEC>(xl + (size_t)sA * M + c0, wA);
            edge_load<VEC>(xl + (size_t)sB * M + c0, wB);
            edge_load<VEC>(xl + (size_t)sC * M + c0, wC);
            edge_load<VEC>(xl + (size_t)sD * M + c0, wD);
            edge_acc<VEC>(acc, eA, wA);
            edge_acc<VEC>(acc, eB, wB);
            edge_acc<VEC>(acc, eC, wC);
            edge_acc<VEC>(acc, eD, wD);
        }
        for (; j < lim; j += 2) {
            int sA = ls[wid][j];
            float eA = le[wid][h][j];
            uint2 wA;
            edge_load<VEC>(xl + (size_t)sA * M + c0, wA);
            edge_acc<VEC>(acc, eA, wA);
        }
    }

    // ---- reductions ----
#pragma unroll
    for (int off = 32; off > 0; off >>= 1) {
        den0 += __shfl_xor(den0, off, 64);
        if constexpr (H == 2) den1 += __shfl_xor(den1, off, 64);
    }
#pragma unroll
    for (int v = 0; v < VEC; v++) acc[v] += __shfl_xor(acc[v], 32, 64);

    float den = ((H == 2 && h == 1) ? den1 : den0) + ex_self + 1e-16f;
    float inv = 1.f / den;
    if (half == 0) {
        unsigned short* op = out + (size_t)n * M + c0;
        if constexpr (VEC == 8) {
            uint4 o;
            o.x = packbf(acc[0] * inv + bias[c0 + 0], acc[1] * inv + bias[c0 + 1]);
            o.y = packbf(acc[2] * inv + bias[c0 + 2], acc[3] * inv + bias[c0 + 3]);
            o.z = packbf(acc[4] * inv + bias[c0 + 4], acc[5] * inv + bias[c0 + 5]);
            o.w = packbf(acc[6] * inv + bias[c0 + 6], acc[7] * inv + bias[c0 + 7]);
            *(uint4*)op = o;
        } else {
            uint2 o;
            o.x = packbf(acc[0] * inv + bias[c0 + 0], acc[1] * inv + bias[c0 + 1]);
            o.y = packbf(acc[2] * inv + bias[c0 + 2], acc[3] * inv + bias[c0 + 3]);
            *(uint2*)op = o;
        }
    }
}

// ---------------- edge sort by dst (counting sort) ----------------
__global__ void k_count(const int* __restrict__ dst, int* __restrict__ count) {
    int e = blockIdx.x * blockDim.x + threadIdx.x;
    if (e < EE) atomicAdd(&count[dst[e]], 1);
}

// single-block exclusive scan (1024 threads, wave-shuffle + carry)
__global__ __launch_bounds__(1024) void k_scan(const int* __restrict__ in,
                                               int* __restrict__ out, int n) {
    __shared__ int wsum[16];
    int tid = threadIdx.x;
    int wid = tid >> 6, lane = tid & 63;
    int carry = 0;
    for (int base = 0; base < n; base += 1024) {
        int i = base + tid;
        int v = (i < n) ? in[i] : 0;
        int x = v;
#pragma unroll
        for (int off = 1; off < 64; off <<= 1) {
            int y = __shfl_up(x, off, 64);
            if (lane >= off) x += y;
        }
        if (lane == 63) wsum[wid] = x;
        __syncthreads();
        if (wid == 0) {
            int t = (lane < 16) ? wsum[lane] : 0;
#pragma unroll
            for (int off = 1; off < 16; off <<= 1) {
                int y = __shfl_up(t, off, 64);
                if (lane >= off) t += y;
            }
            if (lane < 16) wsum[lane] = t;
        }
        __syncthreads();
        int woff = (wid > 0) ? wsum[wid - 1] : 0;
        if (i < n) out[i] = carry + woff + x - v;
        carry += wsum[15];
        __syncthreads();
    }
}

__global__ void k_scatter(const int* __restrict__ src, const int* __restrict__ dst,
                          const int* __restrict__ offsets, int* __restrict__ cursor,
                          int* __restrict__ ssrc) {
    int e = blockIdx.x * blockDim.x + threadIdx.x;
    if (e >= EE) return;
    int d = dst[e];
    int p = offsets[d] + atomicAdd(&cursor[d], 1);
    ssrc[p] = src[e];
}

// ---------------- batch norm: 256-block partial stats (f32, no atomics) ----------------
__global__ __launch_bounds__(256) void k_bn_stats(const unsigned short* __restrict__ h,
                                                  float* __restrict__ part) {
    int tid = threadIdx.x;
    int bid = blockIdx.x;      // 256 blocks
    int c0 = (tid & 31) * 8;   // 8 cols per thread
    int rg = tid >> 5;         // 8 row groups
    float s[8] = {}, s2[8] = {};
    for (int r = bid * 8 + rg; r < NN; r += 2048) {
        uint4 v = *(const uint4*)(h + (size_t)r * 256 + c0);
        float f;
        f = bflo(v.x); s[0] += f; s2[0] += f * f;
        f = bfhi(v.x); s[1] += f; s2[1] += f * f;
        f = bflo(v.y); s[2] += f; s2[2] += f * f;
        f = bfhi(v.y); s[3] += f; s2[3] += f * f;
        f = bflo(v.z); s[4] += f; s2[4] += f * f;
        f = bfhi(v.z); s[5] += f; s2[5] += f * f;
        f = bflo(v.w); s[6] += f; s2[6] += f * f;
        f = bfhi(v.w); s[7] += f; s2[7] += f * f;
    }
    __shared__ float sb[8][256];
#pragma unroll
    for (int v = 0; v < 8; v++) sb[rg][c0 + v] = s[v];
    __syncthreads();
    float tot = 0.f;
#pragma unroll
    for (int g = 0; g < 8; g++) tot += sb[g][tid];
    part[bid * 512 + tid] = tot;
    __syncthreads();
#pragma unroll
    for (int v = 0; v < 8; v++) sb[rg][c0 + v] = s2[v];
    __syncthreads();
    tot = 0.f;
#pragma unroll
    for (int g = 0; g < 8; g++) tot += sb[g][tid];
    part[bid * 512 + 256 + tid] = tot;
}

__global__ void k_bn_finalize(const float* __restrict__ part, const float* __restrict__ g,
                              const float* __restrict__ be, float* __restrict__ scale,
                              float* __restrict__ shift) {
    int t = threadIdx.x;  // 256
    float s = 0.f, s2 = 0.f;
    for (int b = 0; b < 256; b++) {
        s += part[b * 512 + t];
        s2 += part[b * 512 + 256 + t];
    }
    float mu = s / (float)NN;
    float var = s2 / (float)NN - mu * mu;
    float sc = g[t] * rsqrtf(var + BN_EPS);
    scale[t] = sc;
    shift[t] = be[t] - mu * sc;
}

__global__ void k_bn_apply(unsigned short* __restrict__ h, const float* __restrict__ scale,
                           const float* __restrict__ shift) {
    int i = blockIdx.x * blockDim.x + threadIdx.x;
    int stride = gridDim.x * blockDim.x;
    int total = NN * 256 / 8;
    uint4* h4 = (uint4*)h;
    for (; i < total; i += stride) {
        uint4 v = h4[i];
        int t = (i * 8) & 255;
        float f0 = fmaxf(bflo(v.x) * scale[t + 0] + shift[t + 0], 0.f);
        float f1 = fmaxf(bfhi(v.x) * scale[t + 1] + shift[t + 1], 0.f);
        float f2 = fmaxf(bflo(v.y) * scale[t + 2] + shift[t + 2], 0.f);
        float f3 = fmaxf(bfhi(v.y) * scale[t + 3] + shift[t + 3], 0.f);
        float f4 = fmaxf(bflo(v.z) * scale[t + 4] + shift[t + 4], 0.f);
        float f5 = fmaxf(bfhi(v.z) * scale[t + 5] + shift[t + 5], 0.f);
        float f6 = fmaxf(bflo(v.w) * scale[t + 6] + shift[t + 6], 0.f);
        float f7 = fmaxf(bfhi(v.w) * scale[t + 7] + shift[t + 7], 0.f);
        v.x = packbf(f0, f1);
        v.y = packbf(f2, f3);
        v.z = packbf(f4, f5);
        v.w = packbf(f6, f7);
        h4[i] = v;
    }
}

// ---------------- pooling + final linear ----------------
#define POOL_ROWS 128
__global__ void k_pool(const unsigned short* __restrict__ h3, const int* __restrict__ batch,
                       float* __restrict__ pooled, int* __restrict__ cnt) {
    int t = threadIdx.x;  // 128
    int r0 = blockIdx.x * POOL_ROWS;
    if (r0 >= NN) return;
    int rend = min(r0 + POOL_ROWS, NN);
    float acc = 0.f;
    int c_acc = 0;
    int g_cur = batch[r0];
    for (int r = r0; r < rend; r++) {
        int g = batch[r];
        if (g != g_cur) {
            atomicAdd(&pooled[g_cur * 128 + t], acc);
            if (t == 0) atomicAdd(&cnt[g_cur], c_acc);
            acc = 0.f;
            c_acc = 0;
            g_cur = g;
        }
        acc += bf2f(h3[(size_t)r * 128 + t]);
        c_acc++;
    }
    atomicAdd(&pooled[g_cur * 128 + t], acc);
    if (t == 0) atomicAdd(&cnt[g_cur], c_acc);
}

__global__ void k_final(const float* __restrict__ pooled, const int* __restrict__ cnt,
                        const float* __restrict__ Wlin, const float* __restrict__ blin,
                        float* __restrict__ out) {
    int g = blockIdx.x;   // 64
    int o = threadIdx.x;  // 64
    float c = (float)max(cnt[g], 1);
    float acc = 0.f;
    for (int k = 0; k < 128; k++) acc += pooled[g * 128 + k] * Wlin[k * 64 + o];
    out[g * 64 + o] = acc / c + blin[o];
}

// ---------------- host ----------------
extern "C" void kernel_launch(void* const* d_in, const int* in_sizes, int n_in,
                              void* d_out, int out_size, void* d_ws, size_t ws_size,
                              hipStream_t stream) {
    const float* x = (const float*)d_in[0];
    const int* ei = (const int*)d_in[1];
    const int* batch = (const int*)d_in[2];
    const float* W1 = (const float*)d_in[3];
    const float* as1 = (const float*)d_in[4];
    const float* ad1 = (const float*)d_in[5];
    const float* b1 = (const float*)d_in[6];
    const float* g1 = (const float*)d_in[7];
    const float* be1 = (const float*)d_in[8];
    const float* W2 = (const float*)d_in[9];
    const float* as2 = (const float*)d_in[10];
    const float* ad2 = (const float*)d_in[11];
    const float* b2 = (const float*)d_in[12];
    const float* g2 = (const float*)d_in[13];
    const float* be2 = (const float*)d_in[14];
    const float* W3 = (const float*)d_in[15];
    const float* as3 = (const float*)d_in[16];
    const float* ad3 = (const float*)d_in[17];
    const float* b3 = (const float*)d_in[18];
    const float* Wlin = (const float*)d_in[19];
    const float* blin = (const float*)d_in[20];
    float* out = (float*)d_out;

    const int* src = ei;
    const int* dst = ei + EE;

    char* ws = (char*)d_ws;
    size_t off = 0;
    auto alloc = [&](size_t bytes) -> void* {
        void* p = (void*)(ws + off);
        off = (off + bytes + 255) & ~(size_t)255;
        return p;
    };
    unsigned short* xb = (unsigned short*)alloc((size_t)NN * 512 * 2);
    unsigned char* xl = (unsigned char*)alloc((size_t)NN * 256);
    unsigned short* hbuf = (unsigned short*)alloc((size_t)NN * 256 * 2);
    unsigned short* Wt1 = (unsigned short*)alloc((size_t)256 * 512 * 2);
    unsigned short* Wt2 = (unsigned short*)alloc((size_t)256 * 256 * 2);
    unsigned short* Wt3 = (unsigned short*)alloc((size_t)128 * 256 * 2);
    float* es = (float*)alloc((size_t)NN * 2 * 4);
    float* ed = (float*)alloc((size_t)NN * 2 * 4);
    int* cc = (int*)alloc((size_t)2 * NN * 4);  // count | cursor (one memset)
    int* count = cc;
    int* cursor = cc + NN;
    int* offsets = (int*)alloc((size_t)NN * 4);
    int* ssrc = (int*)alloc((size_t)EE * 4);
    float* bnpart = (float*)alloc((size_t)256 * 512 * 4);
    float* bnscale = (float*)alloc(256 * 4);
    float* bnshift = (float*)alloc(256 * 4);
    float* pooled = (float*)alloc(64 * 128 * 4);  // cnt directly follows (aligned)
    int* cnt = (int*)alloc(64 * 4);

    const int EB = (EE + 255) / 256;  // 3125
    const int AGB = (NN + 3) / 4;     // 12500
    const int NRB = (NN + 127) / 128; // 391

    // ---- one-time input prep (convert + transposes fused) ----
    k_prep<<<2048, 256, 0, stream>>>(x, xb, W1, W2, W3, Wt1, Wt2, Wt3);

    // ---- sort edges by dst (once; graph shared across layers) ----
    k_memset32<<<128, 256, 0, stream>>>(cc, 0, 2 * NN);
    k_count<<<EB, 256, 0, stream>>>(dst, count);
    k_scan<<<1, 1024, 0, stream>>>(count, offsets, NN);
    k_scatter<<<EB, 256, 0, stream>>>(src, dst, offsets, cursor, ssrc);

    auto bn_relu = [&](unsigned short* h, const float* g_, const float* be_) {
        k_bn_stats<<<256, 256, 0, stream>>>(h, bnpart);
        k_bn_finalize<<<1, 256, 0, stream>>>(bnpart, g_, be_, bnscale, bnshift);
        k_bn_apply<<<1024, 256, 0, stream>>>(h, bnscale, bnshift);
    };

    // ---- layer 1: 512 -> [2,128] concat 256 ----
    k_gemm_mfma<<<2 * NRB, 256, 0, stream>>>(xb, Wt1, xl, as1, ad1, es, ed, NN, 512, 256, 2, 2);
    k_aggregate<8, 2><<<AGB, 256, 0, stream>>>(xl, es, ed, offsets, count, ssrc, b1, hbuf);
    bn_relu(hbuf, g1, be1);

    // ---- layer 2: 256 -> 256 ----
    k_gemm_mfma<<<2 * NRB, 256, 0, stream>>>(hbuf, Wt2, xl, as2, ad2, es, ed, NN, 256, 256, 2, 2);
    k_aggregate<8, 2><<<AGB, 256, 0, stream>>>(xl, es, ed, offsets, count, ssrc, b2, hbuf);
    bn_relu(hbuf, g2, be2);

    // ---- layer 3: 256 -> 128, 1 head ----
    k_gemm_mfma<<<NRB, 256, 0, stream>>>(hbuf, Wt3, xl, as3, ad3, es, ed, NN, 256, 128, 1, 1);
    k_aggregate<4, 1><<<AGB, 256, 0, stream>>>(xl, es, ed, offsets, count, ssrc, b3, hbuf);

    // ---- global mean pool + final linear ----
    k_memset32<<<33, 256, 0, stream>>>((int*)pooled, 0, 64 * 128 + 64);
    k_pool<<<(NN + POOL_ROWS - 1) / POOL_ROWS, 128, 0, stream>>>(hbuf, batch, pooled, cnt);
    k_final<<<GG, 64, 0, stream>>>(pooled, cnt, Wlin, blin, out);
}

// Round 13
// 429.505 us; speedup vs baseline: 1.7695x; 1.0918x over previous
//
#include <hip/hip_runtime.h>
#include <cstdint>
#include <math.h>

#define NN 50000
#define EE 800000
#define GG 64
#define NEG_SLOPE 0.2f
#define BN_EPS 1e-5f

typedef short bf16x8 __attribute__((ext_vector_type(8)));
typedef float f32x4 __attribute__((ext_vector_type(4)));

// ---------------- utility ----------------
__global__ void k_memset32(int* p, int val, int n) {
    int i = blockIdx.x * blockDim.x + threadIdx.x;
    int stride = gridDim.x * blockDim.x;
    for (; i < n; i += stride) p[i] = val;
}

__device__ inline float leaky(float x) { return x > 0.f ? x : NEG_SLOPE * x; }

__device__ inline unsigned short f2bf(float f) {
    union { float f; uint32_t u; } v;
    v.f = f;
    uint32_t u = v.u;
    return (unsigned short)((u + 0x7fffu + ((u >> 16) & 1u)) >> 16);
}

__device__ inline float bf2f(unsigned short u) {
    union { uint32_t u; float f; } v;
    v.u = (uint32_t)u << 16;
    return v.f;
}
__device__ inline float bflo(uint32_t u) { return __uint_as_float(u << 16); }
__device__ inline float bfhi(uint32_t u) { return __uint_as_float(u & 0xffff0000u); }
__device__ inline uint32_t packbf(float a, float b) {
    return (uint32_t)f2bf(a) | ((uint32_t)f2bf(b) << 16);
}

__device__ inline unsigned char f2fp8(float v) {
    int p = __builtin_amdgcn_cvt_pk_fp8_f32(v, v, 0, false);
    return (unsigned char)(p & 0xff);
}

__device__ inline void gload16(const void* g, void* l) {
    __builtin_amdgcn_global_load_lds(
        (const __attribute__((address_space(1))) unsigned int*)g,
        (__attribute__((address_space(3))) unsigned int*)l, 16, 0, 0);
}

// ---------------- one-time prep: x->bf16 convert + all W transposes ----------------
__global__ void k_prep(const float* __restrict__ x, unsigned short* __restrict__ xb,
                       const float* __restrict__ W1, const float* __restrict__ W2,
                       const float* __restrict__ W3, unsigned short* __restrict__ Wt1,
                       unsigned short* __restrict__ Wt2, unsigned short* __restrict__ Wt3) {
    int t0 = blockIdx.x * blockDim.x + threadIdx.x;
    int stride = gridDim.x * blockDim.x;
    const int n4 = NN * 512 / 4;
    for (int i = t0; i < n4; i += stride) {
        float4 v = ((const float4*)x)[i];
        uint2 o;
        o.x = packbf(v.x, v.y);
        o.y = packbf(v.z, v.w);
        ((uint2*)xb)[i] = o;
    }
    const int TR = 512 * 256 + 256 * 256 + 256 * 128;
    for (int idx = t0; idx < TR; idx += stride) {
        if (idx < 512 * 256) {
            int k = idx >> 8, m_ = idx & 255;
            Wt1[(size_t)m_ * 512 + k] = f2bf(W1[idx]);
        } else if (idx < 512 * 256 + 256 * 256) {
            int i = idx - 512 * 256;
            int k = i >> 8, m_ = i & 255;
            Wt2[(size_t)m_ * 256 + k] = f2bf(W2[i]);
        } else {
            int i = idx - (512 * 256 + 256 * 256);
            int k = i >> 7, m_ = i & 127;
            Wt3[(size_t)m_ * 256 + k] = f2bf(W3[i]);
        }
    }
}

// ---------------- MFMA GEMM (m97 structure), fp8 C, fused scores epilogue ----------------
__global__ __launch_bounds__(256) void k_gemm_mfma(
        const unsigned short* __restrict__ A, const unsigned short* __restrict__ Bt,
        unsigned char* __restrict__ C8,
        const float* __restrict__ asrc, const float* __restrict__ adst,
        float* __restrict__ es, float* __restrict__ ed,
        int NR, int K, int M, int H, int gxc) {
    __shared__ unsigned short As[2][128 * 32];
    __shared__ unsigned short Bs[2][128 * 32];
    __shared__ float esA[2][128], edA[2][128];
    int tid = threadIdx.x;
    int wave = tid >> 6, lane = tid & 63;
    int r16 = lane & 15, kg = lane >> 4;
    int wr = wave >> 1, wc = wave & 1;

    // bijective XCD swizzle (m204)
    int nwg = gridDim.x;
    int nb = blockIdx.x;
    int q = nwg >> 3, r = nwg & 7;
    int xcd = nb & 7, ii = nb >> 3;
    int w = (xcd < r ? xcd * (q + 1) : r * (q + 1) + (xcd - r) * q) + ii;
    int rowBase = (w / gxc) * 128;
    int colBase = (w % gxc) * 128;

    const unsigned short* gA[2];
    const unsigned short* gB[2];
#pragma unroll
    for (int it = 0; it < 2; ++it) {
        int j = it * 256 + tid;
        int row = j >> 2, slot = j & 3;
        int ss = slot ^ ((row >> 1) & 3);  // inverse swizzle on source
        int rg = rowBase + row;
        if (rg >= NR) rg = NR - 1;  // clamp (garbage rows never written out)
        gA[it] = A + (size_t)rg * K + ss * 8;
        gB[it] = Bt + (size_t)(colBase + row) * K + ss * 8;
    }

    auto STAGE = [&](int buf, int k0) {
#pragma unroll
        for (int it = 0; it < 2; ++it) {
            unsigned short* lbase = &As[buf][(it * 256 + wave * 64) * 8];
            gload16(gA[it] + k0, lbase);
            unsigned short* lbase2 = &Bs[buf][(it * 256 + wave * 64) * 8];
            gload16(gB[it] + k0, lbase2);
        }
    };

    f32x4 acc[4][4] = {};
    int nt = K >> 5;
    STAGE(0, 0);
    __syncthreads();
    for (int t = 0; t < nt; ++t) {
        int cur = t & 1;
        if (t + 1 < nt) STAGE(cur ^ 1, (t + 1) << 5);  // issue before compute
        bf16x8 af[4], bfr[4];
#pragma unroll
        for (int m = 0; m < 4; m++) {
            int row = wr * 64 + m * 16 + r16;
            af[m] = *(const bf16x8*)&As[cur][row * 32 + (kg ^ ((row >> 1) & 3)) * 8];
        }
#pragma unroll
        for (int n = 0; n < 4; n++) {
            int row = wc * 64 + n * 16 + r16;
            bfr[n] = *(const bf16x8*)&Bs[cur][row * 32 + (kg ^ ((row >> 1) & 3)) * 8];
        }
#pragma unroll
        for (int m = 0; m < 4; m++)
#pragma unroll
            for (int n = 0; n < 4; n++)
                acc[m][n] = __builtin_amdgcn_mfma_f32_16x16x32_bf16(af[m], bfr[n], acc[m][n], 0, 0, 0);
        __syncthreads();
    }
    // ---- C write (fp8 e4m3) ----
    int crow0 = rowBase + wr * 64;
    int ccol = colBase + wc * 64 + r16;
#pragma unroll
    for (int m = 0; m < 4; m++) {
#pragma unroll
        for (int j = 0; j < 4; j++) {
            int row = crow0 + m * 16 + kg * 4 + j;
            if (row < NR) {
#pragma unroll
                for (int n = 0; n < 4; n++)
                    C8[(size_t)row * M + ccol + n * 16] = f2fp8(acc[m][n][j]);
            }
        }
    }
    // ---- fused attention-score epilogue (f32 acc, full precision) ----
    int h_blk = colBase >> 7;
    float as_[4], ad_[4];
#pragma unroll
    for (int n = 0; n < 4; n++) {
        int ch = wc * 64 + n * 16 + r16;
        as_[n] = asrc[h_blk * 128 + ch];
        ad_[n] = adst[h_blk * 128 + ch];
    }
#pragma unroll
    for (int m = 0; m < 4; m++) {
#pragma unroll
        for (int j = 0; j < 4; j++) {
            float e1 = 0.f, e2 = 0.f;
#pragma unroll
            for (int n = 0; n < 4; n++) {
                e1 += acc[m][n][j] * as_[n];
                e2 += acc[m][n][j] * ad_[n];
            }
#pragma unroll
            for (int mask = 1; mask < 16; mask <<= 1) {
                e1 += __shfl_xor(e1, mask, 64);
                e2 += __shfl_xor(e2, mask, 64);
            }
            if (r16 == 0) {
                int lr = wr * 64 + m * 16 + kg * 4 + j;
                esA[wc][lr] = e1;
                edA[wc][lr] = e2;
            }
        }
    }
    __syncthreads();
    if (tid < 128) {
        int row = rowBase + tid;
        if (row < NR) {
            es[row * H + h_blk] = esA[0][tid] + esA[1][tid];
            ed[row * H + h_blk] = edA[0][tid] + edA[1][tid];
        }
    }
}

// ---------------- fused softmax + aggregation (no-max form, fp8 gather) ----------------
template <int VEC>
__device__ inline void edge_load(const unsigned char* rp, uint2& w) {
    if constexpr (VEC == 8) {
        w = *(const uint2*)rp;
    } else {
        w.x = *(const unsigned int*)rp;
        w.y = 0;
    }
}

template <int VEC>
__device__ inline void edge_acc(float* acc, float e, const uint2& w) {
    auto p0 = __builtin_amdgcn_cvt_pk_f32_fp8(w.x, false);
    auto p1 = __builtin_amdgcn_cvt_pk_f32_fp8(w.x, true);
    acc[0] += e * p0[0]; acc[1] += e * p0[1];
    acc[2] += e * p1[0]; acc[3] += e * p1[1];
    if constexpr (VEC == 8) {
        auto p2 = __builtin_amdgcn_cvt_pk_f32_fp8(w.y, false);
        auto p3 = __builtin_amdgcn_cvt_pk_f32_fp8(w.y, true);
        acc[4] += e * p2[0]; acc[5] += e * p2[1];
        acc[6] += e * p3[0]; acc[7] += e * p3[1];
    }
}

template <int VEC, int H>  // M = 32*VEC cols; lanes 0-31 even edges, 32-63 odd edges
__global__ __launch_bounds__(256) void k_aggregate(
        const unsigned char* __restrict__ xl, const float* __restrict__ es,
        const float* __restrict__ ed, const int* __restrict__ offsets,
        const int* __restrict__ count, const int* __restrict__ ssrc,
        const float* __restrict__ bias, unsigned short* __restrict__ out) {
    const int M = 32 * VEC;
    int wid = threadIdx.x >> 6;
    int n = blockIdx.x * 4 + wid;
    if (n >= NN) return;
    int lane = threadIdx.x & 63;
    int half = lane >> 5, l32 = lane & 31;
    int c0 = l32 * VEC;
    int h = (H == 2) ? (c0 >> 7) : 0;

    float edn0, edn1 = 0.f, self0, self1 = 0.f;
    if constexpr (H == 2) {
        float2 edp = *(const float2*)&ed[n * 2];
        float2 esp = *(const float2*)&es[n * 2];
        edn0 = edp.x; edn1 = edp.y;
        self0 = __expf(leaky(esp.x + edn0));
        self1 = __expf(leaky(esp.y + edn1));
    } else {
        edn0 = ed[n];
        self0 = __expf(leaky(es[n] + edn0));
    }
    float ex_self = (H == 2 && h == 1) ? self1 : self0;

    float acc[VEC] = {};
    if (half == 0) {
        uint2 w;
        edge_load<VEC>(xl + (size_t)n * M + c0, w);
        edge_acc<VEC>(acc, ex_self, w);
    }

    // ---- single pass: cooperative score -> wave LDS, half-wave gather ----
    __shared__ int ls[4][64];
    __shared__ float le[4][H][64];
    float den0 = 0.f, den1 = 0.f;
    int s0 = offsets[n], cnte = count[n];
    for (int base = 0; base < cnte; base += 64) {
        int i = base + lane;
        int s = 0;
        float e0 = 0.f, e1 = 0.f;
        if (i < cnte) {
            s = ssrc[s0 + i];
            if constexpr (H == 2) {
                float2 esp = *(const float2*)&es[s * 2];
                e0 = __expf(leaky(esp.x + edn0)); den0 += e0;
                e1 = __expf(leaky(esp.y + edn1)); den1 += e1;
            } else {
                e0 = __expf(leaky(es[s] + edn0)); den0 += e0;
            }
        }
        ls[wid][lane] = s;
        le[wid][0][lane] = e0;
        if constexpr (H == 2) le[wid][1][lane] = e1;
        asm volatile("s_waitcnt lgkmcnt(0)" ::: "memory");
        int lim = min(64, cnte - base);
        int j = half;
        for (; j + 7 < lim; j += 8) {  // 4 independent edges in flight
            int sA = ls[wid][j], sB = ls[wid][j + 2], sC = ls[wid][j + 4], sD = ls[wid][j + 6];
            float eA = le[wid][h][j], eB = le[wid][h][j + 2];
            float eC = le[wid][h][j + 4], eD = le[wid][h][j + 6];
            uint2 wA, wB, wC, wD;
            edge_load<VEC>(xl + (size_t)sA * M + c0, wA);
            edge_load<VEC>(xl + (size_t)sB * M + c0, wB);
            edge_load<VEC>(xl + (size_t)sC * M + c0, wC);
            edge_load<VEC>(xl + (size_t)sD * M + c0, wD);
            edge_acc<VEC>(acc, eA, wA);
            edge_acc<VEC>(acc, eB, wB);
            edge_acc<VEC>(acc, eC, wC);
            edge_acc<VEC>(acc, eD, wD);
        }
        for (; j < lim; j += 2) {
            int sA = ls[wid][j];
            float eA = le[wid][h][j];
            uint2 wA;
            edge_load<VEC>(xl + (size_t)sA * M + c0, wA);
            edge_acc<VEC>(acc, eA, wA);
        }
    }

    // ---- reductions ----
#pragma unroll
    for (int off = 32; off > 0; off >>= 1) {
        den0 += __shfl_xor(den0, off, 64);
        if constexpr (H == 2) den1 += __shfl_xor(den1, off, 64);
    }
#pragma unroll
    for (int v = 0; v < VEC; v++) acc[v] += __shfl_xor(acc[v], 32, 64);

    float den = ((H == 2 && h == 1) ? den1 : den0) + ex_self + 1e-16f;
    float inv = 1.f / den;
    if (half == 0) {
        unsigned short* op = out + (size_t)n * M + c0;
        if constexpr (VEC == 8) {
            uint4 o;
            o.x = packbf(acc[0] * inv + bias[c0 + 0], acc[1] * inv + bias[c0 + 1]);
            o.y = packbf(acc[2] * inv + bias[c0 + 2], acc[3] * inv + bias[c0 + 3]);
            o.z = packbf(acc[4] * inv + bias[c0 + 4], acc[5] * inv + bias[c0 + 5]);
            o.w = packbf(acc[6] * inv + bias[c0 + 6], acc[7] * inv + bias[c0 + 7]);
            *(uint4*)op = o;
        } else {
            uint2 o;
            o.x = packbf(acc[0] * inv + bias[c0 + 0], acc[1] * inv + bias[c0 + 1]);
            o.y = packbf(acc[2] * inv + bias[c0 + 2], acc[3] * inv + bias[c0 + 3]);
            *(uint2*)op = o;
        }
    }
}

// ---------------- edge sort by dst (counting sort) ----------------
__global__ void k_count(const int* __restrict__ dst, int* __restrict__ count) {
    int e = blockIdx.x * blockDim.x + threadIdx.x;
    if (e < EE) atomicAdd(&count[dst[e]], 1);
}

__global__ void k_scan_local(const int* __restrict__ in, int* __restrict__ out_excl,
                             int* __restrict__ bsums, int n) {
    __shared__ int s[256];
    int tid = threadIdx.x;
    int i = blockIdx.x * 256 + tid;
    int v = (i < n) ? in[i] : 0;
    s[tid] = v;
    __syncthreads();
    for (int off = 1; off < 256; off <<= 1) {
        int t_ = (tid >= off) ? s[tid - off] : 0;
        __syncthreads();
        s[tid] += t_;
        __syncthreads();
    }
    if (i < n) out_excl[i] = s[tid] - v;
    if (tid == 255) bsums[blockIdx.x] = s[255];
}

__global__ void k_scan_sums(int* __restrict__ b, int n) {
    __shared__ int s[256];
    int tid = threadIdx.x;
    int v = (tid < n) ? b[tid] : 0;
    s[tid] = v;
    __syncthreads();
    for (int off = 1; off < 256; off <<= 1) {
        int t_ = (tid >= off) ? s[tid - off] : 0;
        __syncthreads();
        s[tid] += t_;
        __syncthreads();
    }
    if (tid < n) b[tid] = s[tid] - v;
}

__global__ void k_scan_add(int* __restrict__ out_excl, const int* __restrict__ bsums, int n) {
    int i = blockIdx.x * 256 + threadIdx.x;
    if (i < n) out_excl[i] += bsums[blockIdx.x];
}

__global__ void k_scatter(const int* __restrict__ src, const int* __restrict__ dst,
                          const int* __restrict__ offsets, int* __restrict__ cursor,
                          int* __restrict__ ssrc) {
    int e = blockIdx.x * blockDim.x + threadIdx.x;
    if (e >= EE) return;
    int d = dst[e];
    int p = offsets[d] + atomicAdd(&cursor[d], 1);
    ssrc[p] = src[e];
}

// ---------------- batch norm: 256-block partial stats (f32, no atomics) ----------------
__global__ __launch_bounds__(256) void k_bn_stats(const unsigned short* __restrict__ h,
                                                  float* __restrict__ part) {
    int tid = threadIdx.x;
    int bid = blockIdx.x;      // 256 blocks
    int c0 = (tid & 31) * 8;   // 8 cols per thread
    int rg = tid >> 5;         // 8 row groups
    float s[8] = {}, s2[8] = {};
    for (int r = bid * 8 + rg; r < NN; r += 2048) {
        uint4 v = *(const uint4*)(h + (size_t)r * 256 + c0);
        float f;
        f = bflo(v.x); s[0] += f; s2[0] += f * f;
        f = bfhi(v.x); s[1] += f; s2[1] += f * f;
        f = bflo(v.y); s[2] += f; s2[2] += f * f;
        f = bfhi(v.y); s[3] += f; s2[3] += f * f;
        f = bflo(v.z); s[4] += f; s2[4] += f * f;
        f = bfhi(v.z); s[5] += f; s2[5] += f * f;
        f = bflo(v.w); s[6] += f; s2[6] += f * f;
        f = bfhi(v.w); s[7] += f; s2[7] += f * f;
    }
    __shared__ float sb[8][256];
#pragma unroll
    for (int v = 0; v < 8; v++) sb[rg][c0 + v] = s[v];
    __syncthreads();
    float tot = 0.f;
#pragma unroll
    for (int g = 0; g < 8; g++) tot += sb[g][tid];
    part[bid * 512 + tid] = tot;
    __syncthreads();
#pragma unroll
    for (int v = 0; v < 8; v++) sb[rg][c0 + v] = s2[v];
    __syncthreads();
    tot = 0.f;
#pragma unroll
    for (int g = 0; g < 8; g++) tot += sb[g][tid];
    part[bid * 512 + 256 + tid] = tot;
}

__global__ void k_bn_finalize(const float* __restrict__ part, const float* __restrict__ g,
                              const float* __restrict__ be, float* __restrict__ scale,
                              float* __restrict__ shift) {
    int t = threadIdx.x;  // 256
    float s = 0.f, s2 = 0.f;
    for (int b = 0; b < 256; b++) {
        s += part[b * 512 + t];
        s2 += part[b * 512 + 256 + t];
    }
    float mu = s / (float)NN;
    float var = s2 / (float)NN - mu * mu;
    float sc = g[t] * rsqrtf(var + BN_EPS);
    scale[t] = sc;
    shift[t] = be[t] - mu * sc;
}

__global__ void k_bn_apply(unsigned short* __restrict__ h, const float* __restrict__ scale,
                           const float* __restrict__ shift) {
    int i = blockIdx.x * blockDim.x + threadIdx.x;
    int stride = gridDim.x * blockDim.x;
    int total = NN * 256 / 8;
    uint4* h4 = (uint4*)h;
    for (; i < total; i += stride) {
        uint4 v = h4[i];
        int t = (i * 8) & 255;
        float f0 = fmaxf(bflo(v.x) * scale[t + 0] + shift[t + 0], 0.f);
        float f1 = fmaxf(bfhi(v.x) * scale[t + 1] + shift[t + 1], 0.f);
        float f2 = fmaxf(bflo(v.y) * scale[t + 2] + shift[t + 2], 0.f);
        float f3 = fmaxf(bfhi(v.y) * scale[t + 3] + shift[t + 3], 0.f);
        float f4 = fmaxf(bflo(v.z) * scale[t + 4] + shift[t + 4], 0.f);
        float f5 = fmaxf(bfhi(v.z) * scale[t + 5] + shift[t + 5], 0.f);
        float f6 = fmaxf(bflo(v.w) * scale[t + 6] + shift[t + 6], 0.f);
        float f7 = fmaxf(bfhi(v.w) * scale[t + 7] + shift[t + 7], 0.f);
        v.x = packbf(f0, f1);
        v.y = packbf(f2, f3);
        v.z = packbf(f4, f5);
        v.w = packbf(f6, f7);
        h4[i] = v;
    }
}

// ---------------- pooling + final linear ----------------
#define POOL_ROWS 128
__global__ void k_pool(const unsigned short* __restrict__ h3, const int* __restrict__ batch,
                       float* __restrict__ pooled, int* __restrict__ cnt) {
    int t = threadIdx.x;  // 128
    int r0 = blockIdx.x * POOL_ROWS;
    if (r0 >= NN) return;
    int rend = min(r0 + POOL_ROWS, NN);
    float acc = 0.f;
    int c_acc = 0;
    int g_cur = batch[r0];
    for (int r = r0; r < rend; r++) {
        int g = batch[r];
        if (g != g_cur) {
            atomicAdd(&pooled[g_cur * 128 + t], acc);
            if (t == 0) atomicAdd(&cnt[g_cur], c_acc);
            acc = 0.f;
            c_acc = 0;
            g_cur = g;
        }
        acc += bf2f(h3[(size_t)r * 128 + t]);
        c_acc++;
    }
    atomicAdd(&pooled[g_cur * 128 + t], acc);
    if (t == 0) atomicAdd(&cnt[g_cur], c_acc);
}

__global__ void k_final(const float* __restrict__ pooled, const int* __restrict__ cnt,
                        const float* __restrict__ Wlin, const float* __restrict__ blin,
                        float* __restrict__ out) {
    int g = blockIdx.x;   // 64
    int o = threadIdx.x;  // 64
    float c = (float)max(cnt[g], 1);
    float acc = 0.f;
    for (int k = 0; k < 128; k++) acc += pooled[g * 128 + k] * Wlin[k * 64 + o];
    out[g * 64 + o] = acc / c + blin[o];
}

// ---------------- host ----------------
extern "C" void kernel_launch(void* const* d_in, const int* in_sizes, int n_in,
                              void* d_out, int out_size, void* d_ws, size_t ws_size,
                              hipStream_t stream) {
    const float* x = (const float*)d_in[0];
    const int* ei = (const int*)d_in[1];
    const int* batch = (const int*)d_in[2];
    const float* W1 = (const float*)d_in[3];
    const float* as1 = (const float*)d_in[4];
    const float* ad1 = (const float*)d_in[5];
    const float* b1 = (const float*)d_in[6];
    const float* g1 = (const float*)d_in[7];
    const float* be1 = (const float*)d_in[8];
    const float* W2 = (const float*)d_in[9];
    const float* as2 = (const float*)d_in[10];
    const float* ad2 = (const float*)d_in[11];
    const float* b2 = (const float*)d_in[12];
    const float* g2 = (const float*)d_in[13];
    const float* be2 = (const float*)d_in[14];
    const float* W3 = (const float*)d_in[15];
    const float* as3 = (const float*)d_in[16];
    const float* ad3 = (const float*)d_in[17];
    const float* b3 = (const float*)d_in[18];
    const float* Wlin = (const float*)d_in[19];
    const float* blin = (const float*)d_in[20];
    float* out = (float*)d_out;

    const int* src = ei;
    const int* dst = ei + EE;

    char* ws = (char*)d_ws;
    size_t off = 0;
    auto alloc = [&](size_t bytes) -> void* {
        void* p = (void*)(ws + off);
        off = (off + bytes + 255) & ~(size_t)255;
        return p;
    };
    unsigned short* xb = (unsigned short*)alloc((size_t)NN * 512 * 2);
    unsigned char* xl = (unsigned char*)alloc((size_t)NN * 256);
    unsigned short* hbuf = (unsigned short*)alloc((size_t)NN * 256 * 2);
    unsigned short* Wt1 = (unsigned short*)alloc((size_t)256 * 512 * 2);
    unsigned short* Wt2 = (unsigned short*)alloc((size_t)256 * 256 * 2);
    unsigned short* Wt3 = (unsigned short*)alloc((size_t)128 * 256 * 2);
    float* es = (float*)alloc((size_t)NN * 2 * 4);
    float* ed = (float*)alloc((size_t)NN * 2 * 4);
    int* cc = (int*)alloc((size_t)2 * NN * 4);  // count | cursor (one memset)
    int* count = cc;
    int* cursor = cc + NN;
    int* offsets = (int*)alloc((size_t)NN * 4);
    int* ssrc = (int*)alloc((size_t)EE * 4);
    int* bsums = (int*)alloc(256 * 4);
    float* bnpart = (float*)alloc((size_t)256 * 512 * 4);
    float* bnscale = (float*)alloc(256 * 4);
    float* bnshift = (float*)alloc(256 * 4);
    float* pooled = (float*)alloc(64 * 128 * 4);  // cnt directly follows (aligned)
    int* cnt = (int*)alloc(64 * 4);

    const int EB = (EE + 255) / 256;  // 3125
    const int NB = (NN + 255) / 256;  // 196
    const int AGB = (NN + 3) / 4;     // 12500
    const int NRB = (NN + 127) / 128; // 391

    // ---- one-time input prep (convert + transposes fused) ----
    k_prep<<<2048, 256, 0, stream>>>(x, xb, W1, W2, W3, Wt1, Wt2, Wt3);

    // ---- sort edges by dst (once; graph shared across layers) ----
    k_memset32<<<128, 256, 0, stream>>>(cc, 0, 2 * NN);
    k_count<<<EB, 256, 0, stream>>>(dst, count);
    k_scan_local<<<NB, 256, 0, stream>>>(count, offsets, bsums, NN);
    k_scan_sums<<<1, 256, 0, stream>>>(bsums, NB);
    k_scan_add<<<NB, 256, 0, stream>>>(offsets, bsums, NN);
    k_scatter<<<EB, 256, 0, stream>>>(src, dst, offsets, cursor, ssrc);

    auto bn_relu = [&](unsigned short* h, const float* g_, const float* be_) {
        k_bn_stats<<<256, 256, 0, stream>>>(h, bnpart);
        k_bn_finalize<<<1, 256, 0, stream>>>(bnpart, g_, be_, bnscale, bnshift);
        k_bn_apply<<<1024, 256, 0, stream>>>(h, bnscale, bnshift);
    };

    // ---- layer 1: 512 -> [2,128] concat 256 ----
    k_gemm_mfma<<<2 * NRB, 256, 0, stream>>>(xb, Wt1, xl, as1, ad1, es, ed, NN, 512, 256, 2, 2);
    k_aggregate<8, 2><<<AGB, 256, 0, stream>>>(xl, es, ed, offsets, count, ssrc, b1, hbuf);
    bn_relu(hbuf, g1, be1);

    // ---- layer 2: 256 -> 256 ----
    k_gemm_mfma<<<2 * NRB, 256, 0, stream>>>(hbuf, Wt2, xl, as2, ad2, es, ed, NN, 256, 256, 2, 2);
    k_aggregate<8, 2><<<AGB, 256, 0, stream>>>(xl, es, ed, offsets, count, ssrc, b2, hbuf);
    bn_relu(hbuf, g2, be2);

    // ---- layer 3: 256 -> 128, 1 head ----
    k_gemm_mfma<<<NRB, 256, 0, stream>>>(hbuf, Wt3, xl, as3, ad3, es, ed, NN, 256, 128, 1, 1);
    k_aggregate<4, 1><<<AGB, 256, 0, stream>>>(xl, es, ed, offsets, count, ssrc, b3, hbuf);

    // ---- global mean pool + final linear ----
    k_memset32<<<33, 256, 0, stream>>>((int*)pooled, 0, 64 * 128 + 64);
    k_pool<<<(NN + POOL_ROWS - 1) / POOL_ROWS, 128, 0, stream>>>(hbuf, batch, pooled, cnt);
    k_final<<<GG, 64, 0, stream>>>(pooled, cnt, Wlin, blin, out);
}

// Round 14
// 397.976 us; speedup vs baseline: 1.9097x; 1.0792x over previous
//
#include <hip/hip_runtime.h>
#include <cstdint>
#include <math.h>

#define NN 50000
#define EE 800000
#define GG 64
#define NEG_SLOPE 0.2f
#define BN_EPS 1e-5f

typedef short bf16x8 __attribute__((ext_vector_type(8)));
typedef float f32x4 __attribute__((ext_vector_type(4)));

// ---------------- utility ----------------
__global__ void k_memset32(int* p, int val, int n) {
    int i = blockIdx.x * blockDim.x + threadIdx.x;
    int stride = gridDim.x * blockDim.x;
    for (; i < n; i += stride) p[i] = val;
}

__device__ inline float leaky(float x) { return x > 0.f ? x : NEG_SLOPE * x; }

__device__ inline unsigned short f2bf(float f) {
    union { float f; uint32_t u; } v;
    v.f = f;
    uint32_t u = v.u;
    return (unsigned short)((u + 0x7fffu + ((u >> 16) & 1u)) >> 16);
}

__device__ inline float bf2f(unsigned short u) {
    union { uint32_t u; float f; } v;
    v.u = (uint32_t)u << 16;
    return v.f;
}
__device__ inline float bflo(uint32_t u) { return __uint_as_float(u << 16); }
__device__ inline float bfhi(uint32_t u) { return __uint_as_float(u & 0xffff0000u); }
__device__ inline uint32_t packbf(float a, float b) {
    return (uint32_t)f2bf(a) | ((uint32_t)f2bf(b) << 16);
}

__device__ inline unsigned char f2fp8(float v) {
    int p = __builtin_amdgcn_cvt_pk_fp8_f32(v, v, 0, false);
    return (unsigned char)(p & 0xff);
}

__device__ inline void gload16(const void* g, void* l) {
    __builtin_amdgcn_global_load_lds(
        (const __attribute__((address_space(1))) unsigned int*)g,
        (__attribute__((address_space(3))) unsigned int*)l, 16, 0, 0);
}

// ---------------- one-time prep: x->bf16 convert + all W transposes ----------------
__global__ void k_prep(const float* __restrict__ x, unsigned short* __restrict__ xb,
                       const float* __restrict__ W1, const float* __restrict__ W2,
                       const float* __restrict__ W3, unsigned short* __restrict__ Wt1,
                       unsigned short* __restrict__ Wt2, unsigned short* __restrict__ Wt3) {
    int t0 = blockIdx.x * blockDim.x + threadIdx.x;
    int stride = gridDim.x * blockDim.x;
    const int n4 = NN * 512 / 4;
    for (int i = t0; i < n4; i += stride) {
        float4 v = ((const float4*)x)[i];
        uint2 o;
        o.x = packbf(v.x, v.y);
        o.y = packbf(v.z, v.w);
        ((uint2*)xb)[i] = o;
    }
    const int TR = 512 * 256 + 256 * 256 + 256 * 128;
    for (int idx = t0; idx < TR; idx += stride) {
        if (idx < 512 * 256) {
            int k = idx >> 8, m_ = idx & 255;
            Wt1[(size_t)m_ * 512 + k] = f2bf(W1[idx]);
        } else if (idx < 512 * 256 + 256 * 256) {
            int i = idx - 512 * 256;
            int k = i >> 8, m_ = i & 255;
            Wt2[(size_t)m_ * 256 + k] = f2bf(W2[i]);
        } else {
            int i = idx - (512 * 256 + 256 * 256);
            int k = i >> 7, m_ = i & 127;
            Wt3[(size_t)m_ * 256 + k] = f2bf(W3[i]);
        }
    }
}

// ---------------- MFMA GEMM (m97 structure), fp8 C, fused scores epilogue ----------------
__global__ __launch_bounds__(256) void k_gemm_mfma(
        const unsigned short* __restrict__ A, const unsigned short* __restrict__ Bt,
        unsigned char* __restrict__ C8,
        const float* __restrict__ asrc, const float* __restrict__ adst,
        float* __restrict__ es, float* __restrict__ ed,
        int NR, int K, int M, int H, int gxc) {
    __shared__ unsigned short As[2][128 * 32];
    __shared__ unsigned short Bs[2][128 * 32];
    __shared__ float esA[2][128], edA[2][128];
    int tid = threadIdx.x;
    int wave = tid >> 6, lane = tid & 63;
    int r16 = lane & 15, kg = lane >> 4;
    int wr = wave >> 1, wc = wave & 1;

    // bijective XCD swizzle (m204)
    int nwg = gridDim.x;
    int nb = blockIdx.x;
    int q = nwg >> 3, r = nwg & 7;
    int xcd = nb & 7, ii = nb >> 3;
    int w = (xcd < r ? xcd * (q + 1) : r * (q + 1) + (xcd - r) * q) + ii;
    int rowBase = (w / gxc) * 128;
    int colBase = (w % gxc) * 128;

    const unsigned short* gA[2];
    const unsigned short* gB[2];
#pragma unroll
    for (int it = 0; it < 2; ++it) {
        int j = it * 256 + tid;
        int row = j >> 2, slot = j & 3;
        int ss = slot ^ ((row >> 1) & 3);  // inverse swizzle on source
        int rg = rowBase + row;
        if (rg >= NR) rg = NR - 1;  // clamp (garbage rows never written out)
        gA[it] = A + (size_t)rg * K + ss * 8;
        gB[it] = Bt + (size_t)(colBase + row) * K + ss * 8;
    }

    auto STAGE = [&](int buf, int k0) {
#pragma unroll
        for (int it = 0; it < 2; ++it) {
            unsigned short* lbase = &As[buf][(it * 256 + wave * 64) * 8];
            gload16(gA[it] + k0, lbase);
            unsigned short* lbase2 = &Bs[buf][(it * 256 + wave * 64) * 8];
            gload16(gB[it] + k0, lbase2);
        }
    };

    f32x4 acc[4][4] = {};
    int nt = K >> 5;
    STAGE(0, 0);
    __syncthreads();
    for (int t = 0; t < nt; ++t) {
        int cur = t & 1;
        if (t + 1 < nt) STAGE(cur ^ 1, (t + 1) << 5);  // issue before compute
        bf16x8 af[4], bfr[4];
#pragma unroll
        for (int m = 0; m < 4; m++) {
            int row = wr * 64 + m * 16 + r16;
            af[m] = *(const bf16x8*)&As[cur][row * 32 + (kg ^ ((row >> 1) & 3)) * 8];
        }
#pragma unroll
        for (int n = 0; n < 4; n++) {
            int row = wc * 64 + n * 16 + r16;
            bfr[n] = *(const bf16x8*)&Bs[cur][row * 32 + (kg ^ ((row >> 1) & 3)) * 8];
        }
#pragma unroll
        for (int m = 0; m < 4; m++)
#pragma unroll
            for (int n = 0; n < 4; n++)
                acc[m][n] = __builtin_amdgcn_mfma_f32_16x16x32_bf16(af[m], bfr[n], acc[m][n], 0, 0, 0);
        __syncthreads();
    }
    // ---- C write (fp8 e4m3) ----
    int crow0 = rowBase + wr * 64;
    int ccol = colBase + wc * 64 + r16;
#pragma unroll
    for (int m = 0; m < 4; m++) {
#pragma unroll
        for (int j = 0; j < 4; j++) {
            int row = crow0 + m * 16 + kg * 4 + j;
            if (row < NR) {
#pragma unroll
                for (int n = 0; n < 4; n++)
                    C8[(size_t)row * M + ccol + n * 16] = f2fp8(acc[m][n][j]);
            }
        }
    }
    // ---- fused attention-score epilogue (f32 acc, full precision) ----
    int h_blk = colBase >> 7;
    float as_[4], ad_[4];
#pragma unroll
    for (int n = 0; n < 4; n++) {
        int ch = wc * 64 + n * 16 + r16;
        as_[n] = asrc[h_blk * 128 + ch];
        ad_[n] = adst[h_blk * 128 + ch];
    }
#pragma unroll
    for (int m = 0; m < 4; m++) {
#pragma unroll
        for (int j = 0; j < 4; j++) {
            float e1 = 0.f, e2 = 0.f;
#pragma unroll
            for (int n = 0; n < 4; n++) {
                e1 += acc[m][n][j] * as_[n];
                e2 += acc[m][n][j] * ad_[n];
            }
#pragma unroll
            for (int mask = 1; mask < 16; mask <<= 1) {
                e1 += __shfl_xor(e1, mask, 64);
                e2 += __shfl_xor(e2, mask, 64);
            }
            if (r16 == 0) {
                int lr = wr * 64 + m * 16 + kg * 4 + j;
                esA[wc][lr] = e1;
                edA[wc][lr] = e2;
            }
        }
    }
    __syncthreads();
    if (tid < 128) {
        int row = rowBase + tid;
        if (row < NR) {
            es[row * H + h_blk] = esA[0][tid] + esA[1][tid];
            ed[row * H + h_blk] = edA[0][tid] + edA[1][tid];
        }
    }
}

// ---------------- fused softmax + aggregation (no-max form, fp8 gather) ----------------
template <int VEC>
__device__ inline void edge_load(const unsigned char* rp, uint2& w) {
    if constexpr (VEC == 8) {
        w = *(const uint2*)rp;
    } else {
        w.x = *(const unsigned int*)rp;
        w.y = 0;
    }
}

template <int VEC>
__device__ inline void edge_acc(float* acc, float e, const uint2& w) {
    auto p0 = __builtin_amdgcn_cvt_pk_f32_fp8(w.x, false);
    auto p1 = __builtin_amdgcn_cvt_pk_f32_fp8(w.x, true);
    acc[0] += e * p0[0]; acc[1] += e * p0[1];
    acc[2] += e * p1[0]; acc[3] += e * p1[1];
    if constexpr (VEC == 8) {
        auto p2 = __builtin_amdgcn_cvt_pk_f32_fp8(w.y, false);
        auto p3 = __builtin_amdgcn_cvt_pk_f32_fp8(w.y, true);
        acc[4] += e * p2[0]; acc[5] += e * p2[1];
        acc[6] += e * p3[0]; acc[7] += e * p3[1];
    }
}

template <int VEC, int H>  // M = 32*VEC cols; lanes 0-31 even edges, 32-63 odd edges
__global__ __launch_bounds__(256) void k_aggregate(
        const unsigned char* __restrict__ xl, const float* __restrict__ es,
        const float* __restrict__ ed, const int* __restrict__ offsets,
        const int* __restrict__ count, const int* __restrict__ ssrc,
        const float* __restrict__ bias, unsigned short* __restrict__ out) {
    const int M = 32 * VEC;
    int wid = threadIdx.x >> 6;
    int n = blockIdx.x * 4 + wid;
    if (n >= NN) return;
    int lane = threadIdx.x & 63;
    int half = lane >> 5, l32 = lane & 31;
    int c0 = l32 * VEC;
    int h = (H == 2) ? (c0 >> 7) : 0;

    float edn0, edn1 = 0.f, self0, self1 = 0.f;
    if constexpr (H == 2) {
        float2 edp = *(const float2*)&ed[n * 2];
        float2 esp = *(const float2*)&es[n * 2];
        edn0 = edp.x; edn1 = edp.y;
        self0 = __expf(leaky(esp.x + edn0));
        self1 = __expf(leaky(esp.y + edn1));
    } else {
        edn0 = ed[n];
        self0 = __expf(leaky(es[n] + edn0));
    }
    float ex_self = (H == 2 && h == 1) ? self1 : self0;

    float acc[VEC] = {};
    if (half == 0) {
        uint2 w;
        edge_load<VEC>(xl + (size_t)n * M + c0, w);
        edge_acc<VEC>(acc, ex_self, w);
    }

    // ---- single pass: cooperative score -> wave LDS, half-wave gather ----
    __shared__ int ls[4][64];
    __shared__ float le[4][H][64];
    float den0 = 0.f, den1 = 0.f;
    int s0 = offsets[n], cnte = count[n];
    for (int base = 0; base < cnte; base += 64) {
        int i = base + lane;
        int s = 0;
        float e0 = 0.f, e1 = 0.f;
        if (i < cnte) {
            s = ssrc[s0 + i];
            if constexpr (H == 2) {
                float2 esp = *(const float2*)&es[s * 2];
                e0 = __expf(leaky(esp.x + edn0)); den0 += e0;
                e1 = __expf(leaky(esp.y + edn1)); den1 += e1;
            } else {
                e0 = __expf(leaky(es[s] + edn0)); den0 += e0;
            }
        }
        ls[wid][lane] = s;
        le[wid][0][lane] = e0;
        if constexpr (H == 2) le[wid][1][lane] = e1;
        asm volatile("s_waitcnt lgkmcnt(0)" ::: "memory");
        int lim = min(64, cnte - base);
        int j = half;
        for (; j + 7 < lim; j += 8) {  // 4 independent edges in flight
            int sA = ls[wid][j], sB = ls[wid][j + 2], sC = ls[wid][j + 4], sD = ls[wid][j + 6];
            float eA = le[wid][h][j], eB = le[wid][h][j + 2];
            float eC = le[wid][h][j + 4], eD = le[wid][h][j + 6];
            uint2 wA, wB, wC, wD;
            edge_load<VEC>(xl + (size_t)sA * M + c0, wA);
            edge_load<VEC>(xl + (size_t)sB * M + c0, wB);
            edge_load<VEC>(xl + (size_t)sC * M + c0, wC);
            edge_load<VEC>(xl + (size_t)sD * M + c0, wD);
            edge_acc<VEC>(acc, eA, wA);
            edge_acc<VEC>(acc, eB, wB);
            edge_acc<VEC>(acc, eC, wC);
            edge_acc<VEC>(acc, eD, wD);
        }
        for (; j < lim; j += 2) {
            int sA = ls[wid][j];
            float eA = le[wid][h][j];
            uint2 wA;
            edge_load<VEC>(xl + (size_t)sA * M + c0, wA);
            edge_acc<VEC>(acc, eA, wA);
        }
    }

    // ---- reductions ----
#pragma unroll
    for (int off = 32; off > 0; off >>= 1) {
        den0 += __shfl_xor(den0, off, 64);
        if constexpr (H == 2) den1 += __shfl_xor(den1, off, 64);
    }
#pragma unroll
    for (int v = 0; v < VEC; v++) acc[v] += __shfl_xor(acc[v], 32, 64);

    float den = ((H == 2 && h == 1) ? den1 : den0) + ex_self + 1e-16f;
    float inv = 1.f / den;
    if (half == 0) {
        unsigned short* op = out + (size_t)n * M + c0;
        if constexpr (VEC == 8) {
            uint4 o;
            o.x = packbf(acc[0] * inv + bias[c0 + 0], acc[1] * inv + bias[c0 + 1]);
            o.y = packbf(acc[2] * inv + bias[c0 + 2], acc[3] * inv + bias[c0 + 3]);
            o.z = packbf(acc[4] * inv + bias[c0 + 4], acc[5] * inv + bias[c0 + 5]);
            o.w = packbf(acc[6] * inv + bias[c0 + 6], acc[7] * inv + bias[c0 + 7]);
            *(uint4*)op = o;
        } else {
            uint2 o;
            o.x = packbf(acc[0] * inv + bias[c0 + 0], acc[1] * inv + bias[c0 + 1]);
            o.y = packbf(acc[2] * inv + bias[c0 + 2], acc[3] * inv + bias[c0 + 3]);
            *(uint2*)op = o;
        }
    }
}

// ---------------- edge sort by dst (counting sort) ----------------
// rank[e] = this edge's order among edges with the same dst (free from the count atomic)
__global__ void k_count(const int* __restrict__ dst, int* __restrict__ count,
                        int* __restrict__ rank) {
    int e = blockIdx.x * blockDim.x + threadIdx.x;
    if (e < EE) rank[e] = atomicAdd(&count[dst[e]], 1);
}

__global__ void k_scan_local(const int* __restrict__ in, int* __restrict__ out_excl,
                             int* __restrict__ bsums, int n) {
    __shared__ int s[256];
    int tid = threadIdx.x;
    int i = blockIdx.x * 256 + tid;
    int v = (i < n) ? in[i] : 0;
    s[tid] = v;
    __syncthreads();
    for (int off = 1; off < 256; off <<= 1) {
        int t_ = (tid >= off) ? s[tid - off] : 0;
        __syncthreads();
        s[tid] += t_;
        __syncthreads();
    }
    if (i < n) out_excl[i] = s[tid] - v;
    if (tid == 255) bsums[blockIdx.x] = s[255];
}

__global__ void k_scan_sums(int* __restrict__ b, int n) {
    __shared__ int s[256];
    int tid = threadIdx.x;
    int v = (tid < n) ? b[tid] : 0;
    s[tid] = v;
    __syncthreads();
    for (int off = 1; off < 256; off <<= 1) {
        int t_ = (tid >= off) ? s[tid - off] : 0;
        __syncthreads();
        s[tid] += t_;
        __syncthreads();
    }
    if (tid < n) b[tid] = s[tid] - v;
}

__global__ void k_scan_add(int* __restrict__ out_excl, const int* __restrict__ bsums, int n) {
    int i = blockIdx.x * 256 + threadIdx.x;
    if (i < n) out_excl[i] += bsums[blockIdx.x];
}

// atomic-free scatter: position fully determined by offsets + precomputed rank
__global__ void k_scatter(const int* __restrict__ src, const int* __restrict__ dst,
                          const int* __restrict__ offsets, const int* __restrict__ rank,
                          int* __restrict__ ssrc) {
    int e = blockIdx.x * blockDim.x + threadIdx.x;
    if (e >= EE) return;
    ssrc[offsets[dst[e]] + rank[e]] = src[e];
}

// ---------------- batch norm: 256-block partial stats (f32, no atomics) ----------------
__global__ __launch_bounds__(256) void k_bn_stats(const unsigned short* __restrict__ h,
                                                  float* __restrict__ part) {
    int tid = threadIdx.x;
    int bid = blockIdx.x;      // 256 blocks
    int c0 = (tid & 31) * 8;   // 8 cols per thread
    int rg = tid >> 5;         // 8 row groups
    float s[8] = {}, s2[8] = {};
    for (int r = bid * 8 + rg; r < NN; r += 2048) {
        uint4 v = *(const uint4*)(h + (size_t)r * 256 + c0);
        float f;
        f = bflo(v.x); s[0] += f; s2[0] += f * f;
        f = bfhi(v.x); s[1] += f; s2[1] += f * f;
        f = bflo(v.y); s[2] += f; s2[2] += f * f;
        f = bfhi(v.y); s[3] += f; s2[3] += f * f;
        f = bflo(v.z); s[4] += f; s2[4] += f * f;
        f = bfhi(v.z); s[5] += f; s2[5] += f * f;
        f = bflo(v.w); s[6] += f; s2[6] += f * f;
        f = bfhi(v.w); s[7] += f; s2[7] += f * f;
    }
    __shared__ float sb[8][256];
#pragma unroll
    for (int v = 0; v < 8; v++) sb[rg][c0 + v] = s[v];
    __syncthreads();
    float tot = 0.f;
#pragma unroll
    for (int g = 0; g < 8; g++) tot += sb[g][tid];
    part[bid * 512 + tid] = tot;
    __syncthreads();
#pragma unroll
    for (int v = 0; v < 8; v++) sb[rg][c0 + v] = s2[v];
    __syncthreads();
    tot = 0.f;
#pragma unroll
    for (int g = 0; g < 8; g++) tot += sb[g][tid];
    part[bid * 512 + 256 + tid] = tot;
}

__global__ void k_bn_finalize(const float* __restrict__ part, const float* __restrict__ g,
                              const float* __restrict__ be, float* __restrict__ scale,
                              float* __restrict__ shift) {
    int t = threadIdx.x;  // 256
    float s = 0.f, s2 = 0.f;
    for (int b = 0; b < 256; b++) {
        s += part[b * 512 + t];
        s2 += part[b * 512 + 256 + t];
    }
    float mu = s / (float)NN;
    float var = s2 / (float)NN - mu * mu;
    float sc = g[t] * rsqrtf(var + BN_EPS);
    scale[t] = sc;
    shift[t] = be[t] - mu * sc;
}

__global__ void k_bn_apply(unsigned short* __restrict__ h, const float* __restrict__ scale,
                           const float* __restrict__ shift) {
    int i = blockIdx.x * blockDim.x + threadIdx.x;
    int stride = gridDim.x * blockDim.x;
    int total = NN * 256 / 8;
    uint4* h4 = (uint4*)h;
    for (; i < total; i += stride) {
        uint4 v = h4[i];
        int t = (i * 8) & 255;
        float f0 = fmaxf(bflo(v.x) * scale[t + 0] + shift[t + 0], 0.f);
        float f1 = fmaxf(bfhi(v.x) * scale[t + 1] + shift[t + 1], 0.f);
        float f2 = fmaxf(bflo(v.y) * scale[t + 2] + shift[t + 2], 0.f);
        float f3 = fmaxf(bfhi(v.y) * scale[t + 3] + shift[t + 3], 0.f);
        float f4 = fmaxf(bflo(v.z) * scale[t + 4] + shift[t + 4], 0.f);
        float f5 = fmaxf(bfhi(v.z) * scale[t + 5] + shift[t + 5], 0.f);
        float f6 = fmaxf(bflo(v.w) * scale[t + 6] + shift[t + 6], 0.f);
        float f7 = fmaxf(bfhi(v.w) * scale[t + 7] + shift[t + 7], 0.f);
        v.x = packbf(f0, f1);
        v.y = packbf(f2, f3);
        v.z = packbf(f4, f5);
        v.w = packbf(f6, f7);
        h4[i] = v;
    }
}

// ---------------- pooling + final linear ----------------
#define POOL_ROWS 128
__global__ void k_pool(const unsigned short* __restrict__ h3, const int* __restrict__ batch,
                       float* __restrict__ pooled, int* __restrict__ cnt) {
    int t = threadIdx.x;  // 128
    int r0 = blockIdx.x * POOL_ROWS;
    if (r0 >= NN) return;
    int rend = min(r0 + POOL_ROWS, NN);
    float acc = 0.f;
    int c_acc = 0;
    int g_cur = batch[r0];
    for (int r = r0; r < rend; r++) {
        int g = batch[r];
        if (g != g_cur) {
            atomicAdd(&pooled[g_cur * 128 + t], acc);
            if (t == 0) atomicAdd(&cnt[g_cur], c_acc);
            acc = 0.f;
            c_acc = 0;
            g_cur = g;
        }
        acc += bf2f(h3[(size_t)r * 128 + t]);
        c_acc++;
    }
    atomicAdd(&pooled[g_cur * 128 + t], acc);
    if (t == 0) atomicAdd(&cnt[g_cur], c_acc);
}

__global__ void k_final(const float* __restrict__ pooled, const int* __restrict__ cnt,
                        const float* __restrict__ Wlin, const float* __restrict__ blin,
                        float* __restrict__ out) {
    int g = blockIdx.x;   // 64
    int o = threadIdx.x;  // 64
    float c = (float)max(cnt[g], 1);
    float acc = 0.f;
    for (int k = 0; k < 128; k++) acc += pooled[g * 128 + k] * Wlin[k * 64 + o];
    out[g * 64 + o] = acc / c + blin[o];
}

// ---------------- host ----------------
extern "C" void kernel_launch(void* const* d_in, const int* in_sizes, int n_in,
                              void* d_out, int out_size, void* d_ws, size_t ws_size,
                              hipStream_t stream) {
    const float* x = (const float*)d_in[0];
    const int* ei = (const int*)d_in[1];
    const int* batch = (const int*)d_in[2];
    const float* W1 = (const float*)d_in[3];
    const float* as1 = (const float*)d_in[4];
    const float* ad1 = (const float*)d_in[5];
    const float* b1 = (const float*)d_in[6];
    const float* g1 = (const float*)d_in[7];
    const float* be1 = (const float*)d_in[8];
    const float* W2 = (const float*)d_in[9];
    const float* as2 = (const float*)d_in[10];
    const float* ad2 = (const float*)d_in[11];
    const float* b2 = (const float*)d_in[12];
    const float* g2 = (const float*)d_in[13];
    const float* be2 = (const float*)d_in[14];
    const float* W3 = (const float*)d_in[15];
    const float* as3 = (const float*)d_in[16];
    const float* ad3 = (const float*)d_in[17];
    const float* b3 = (const float*)d_in[18];
    const float* Wlin = (const float*)d_in[19];
    const float* blin = (const float*)d_in[20];
    float* out = (float*)d_out;

    const int* src = ei;
    const int* dst = ei + EE;

    char* ws = (char*)d_ws;
    size_t off = 0;
    auto alloc = [&](size_t bytes) -> void* {
        void* p = (void*)(ws + off);
        off = (off + bytes + 255) & ~(size_t)255;
        return p;
    };
    unsigned short* xb = (unsigned short*)alloc((size_t)NN * 512 * 2);
    unsigned char* xl = (unsigned char*)alloc((size_t)NN * 256);
    unsigned short* hbuf = (unsigned short*)alloc((size_t)NN * 256 * 2);
    unsigned short* Wt1 = (unsigned short*)alloc((size_t)256 * 512 * 2);
    unsigned short* Wt2 = (unsigned short*)alloc((size_t)256 * 256 * 2);
    unsigned short* Wt3 = (unsigned short*)alloc((size_t)128 * 256 * 2);
    float* es = (float*)alloc((size_t)NN * 2 * 4);
    float* ed = (float*)alloc((size_t)NN * 2 * 4);
    int* count = (int*)alloc((size_t)NN * 4);
    int* offsets = (int*)alloc((size_t)NN * 4);
    int* rank = (int*)alloc((size_t)EE * 4);
    int* ssrc = (int*)alloc((size_t)EE * 4);
    int* bsums = (int*)alloc(256 * 4);
    float* bnpart = (float*)alloc((size_t)256 * 512 * 4);
    float* bnscale = (float*)alloc(256 * 4);
    float* bnshift = (float*)alloc(256 * 4);
    float* pooled = (float*)alloc(64 * 128 * 4);  // cnt directly follows (aligned)
    int* cnt = (int*)alloc(64 * 4);

    const int EB = (EE + 255) / 256;  // 3125
    const int NB = (NN + 255) / 256;  // 196
    const int AGB = (NN + 3) / 4;     // 12500
    const int NRB = (NN + 127) / 128; // 391

    // ---- one-time input prep (convert + transposes fused) ----
    k_prep<<<2048, 256, 0, stream>>>(x, xb, W1, W2, W3, Wt1, Wt2, Wt3);

    // ---- sort edges by dst (once; graph shared across layers) ----
    k_memset32<<<64, 256, 0, stream>>>(count, 0, NN);
    k_count<<<EB, 256, 0, stream>>>(dst, count, rank);
    k_scan_local<<<NB, 256, 0, stream>>>(count, offsets, bsums, NN);
    k_scan_sums<<<1, 256, 0, stream>>>(bsums, NB);
    k_scan_add<<<NB, 256, 0, stream>>>(offsets, bsums, NN);
    k_scatter<<<EB, 256, 0, stream>>>(src, dst, offsets, rank, ssrc);

    auto bn_relu = [&](unsigned short* h, const float* g_, const float* be_) {
        k_bn_stats<<<256, 256, 0, stream>>>(h, bnpart);
        k_bn_finalize<<<1, 256, 0, stream>>>(bnpart, g_, be_, bnscale, bnshift);
        k_bn_apply<<<1024, 256, 0, stream>>>(h, bnscale, bnshift);
    };

    // ---- layer 1: 512 -> [2,128] concat 256 ----
    k_gemm_mfma<<<2 * NRB, 256, 0, stream>>>(xb, Wt1, xl, as1, ad1, es, ed, NN, 512, 256, 2, 2);
    k_aggregate<8, 2><<<AGB, 256, 0, stream>>>(xl, es, ed, offsets, count, ssrc, b1, hbuf);
    bn_relu(hbuf, g1, be1);

    // ---- layer 2: 256 -> 256 ----
    k_gemm_mfma<<<2 * NRB, 256, 0, stream>>>(hbuf, Wt2, xl, as2, ad2, es, ed, NN, 256, 256, 2, 2);
    k_aggregate<8, 2><<<AGB, 256, 0, stream>>>(xl, es, ed, offsets, count, ssrc, b2, hbuf);
    bn_relu(hbuf, g2, be2);

    // ---- layer 3: 256 -> 128, 1 head ----
    k_gemm_mfma<<<NRB, 256, 0, stream>>>(hbuf, Wt3, xl, as3, ad3, es, ed, NN, 256, 128, 1, 1);
    k_aggregate<4, 1><<<AGB, 256, 0, stream>>>(xl, es, ed, offsets, count, ssrc, b3, hbuf);

    // ---- global mean pool + final linear ----
    k_memset32<<<33, 256, 0, stream>>>((int*)pooled, 0, 64 * 128 + 64);
    k_pool<<<(NN + POOL_ROWS - 1) / POOL_ROWS, 128, 0, stream>>>(hbuf, batch, pooled, cnt);
    k_final<<<GG, 64, 0, stream>>>(pooled, cnt, Wlin, blin, out);
}

// Round 15
// 391.763 us; speedup vs baseline: 1.9400x; 1.0159x over previous
//
#include <hip/hip_runtime.h>
#include <cstdint>
#include <math.h>

#define NN 50000
#define EE 800000
#define GG 64
#define NEG_SLOPE 0.2f
#define BN_EPS 1e-5f

typedef short bf16x8 __attribute__((ext_vector_type(8)));
typedef float f32x4 __attribute__((ext_vector_type(4)));

// ---------------- utility ----------------
__device__ inline float leaky(float x) { return x > 0.f ? x : NEG_SLOPE * x; }

__device__ inline unsigned short f2bf(float f) {
    union { float f; uint32_t u; } v;
    v.f = f;
    uint32_t u = v.u;
    return (unsigned short)((u + 0x7fffu + ((u >> 16) & 1u)) >> 16);
}

__device__ inline float bf2f(unsigned short u) {
    union { uint32_t u; float f; } v;
    v.u = (uint32_t)u << 16;
    return v.f;
}
__device__ inline float bflo(uint32_t u) { return __uint_as_float(u << 16); }
__device__ inline float bfhi(uint32_t u) { return __uint_as_float(u & 0xffff0000u); }
__device__ inline uint32_t packbf(float a, float b) {
    return (uint32_t)f2bf(a) | ((uint32_t)f2bf(b) << 16);
}

__device__ inline unsigned char f2fp8(float v) {
    int p = __builtin_amdgcn_cvt_pk_fp8_f32(v, v, 0, false);
    return (unsigned char)(p & 0xff);
}

__device__ inline void gload16(const void* g, void* l) {
    __builtin_amdgcn_global_load_lds(
        (const __attribute__((address_space(1))) unsigned int*)g,
        (__attribute__((address_space(3))) unsigned int*)l, 16, 0, 0);
}

// ---------------- one-time prep: x->bf16, W transposes, buffer zeroing ----------------
__global__ void k_prep(const float* __restrict__ x, unsigned short* __restrict__ xb,
                       const float* __restrict__ W1, const float* __restrict__ W2,
                       const float* __restrict__ W3, unsigned short* __restrict__ Wt1,
                       unsigned short* __restrict__ Wt2, unsigned short* __restrict__ Wt3,
                       int* __restrict__ count, float* __restrict__ pooled_and_cnt) {
    int t0 = blockIdx.x * blockDim.x + threadIdx.x;
    int stride = gridDim.x * blockDim.x;
    const int n4 = NN * 512 / 4;
    for (int i = t0; i < n4; i += stride) {
        float4 v = ((const float4*)x)[i];
        uint2 o;
        o.x = packbf(v.x, v.y);
        o.y = packbf(v.z, v.w);
        ((uint2*)xb)[i] = o;
    }
    const int TR = 512 * 256 + 256 * 256 + 256 * 128;
    for (int idx = t0; idx < TR; idx += stride) {
        if (idx < 512 * 256) {
            int k = idx >> 8, m_ = idx & 255;
            Wt1[(size_t)m_ * 512 + k] = f2bf(W1[idx]);
        } else if (idx < 512 * 256 + 256 * 256) {
            int i = idx - 512 * 256;
            int k = i >> 8, m_ = i & 255;
            Wt2[(size_t)m_ * 256 + k] = f2bf(W2[i]);
        } else {
            int i = idx - (512 * 256 + 256 * 256);
            int k = i >> 7, m_ = i & 127;
            Wt3[(size_t)m_ * 256 + k] = f2bf(W3[i]);
        }
    }
    // zero edge-count histogram (used by k_count this call)
    for (int i = t0; i < NN; i += stride) count[i] = 0;
    // zero pooled accumulators + cnt (consumed by k_pool/k_final at end of this call)
    for (int i = t0; i < 64 * 128 + 64; i += stride) pooled_and_cnt[i] = 0.f;
}

// ---------------- MFMA GEMM (m97 structure), fp8 C, fused scores epilogue ----------------
__global__ __launch_bounds__(256) void k_gemm_mfma(
        const unsigned short* __restrict__ A, const unsigned short* __restrict__ Bt,
        unsigned char* __restrict__ C8,
        const float* __restrict__ asrc, const float* __restrict__ adst,
        float* __restrict__ es, float* __restrict__ ed,
        int NR, int K, int M, int H, int gxc) {
    __shared__ unsigned short As[2][128 * 32];
    __shared__ unsigned short Bs[2][128 * 32];
    __shared__ float esA[2][128], edA[2][128];
    int tid = threadIdx.x;
    int wave = tid >> 6, lane = tid & 63;
    int r16 = lane & 15, kg = lane >> 4;
    int wr = wave >> 1, wc = wave & 1;

    // bijective XCD swizzle (m204)
    int nwg = gridDim.x;
    int nb = blockIdx.x;
    int q = nwg >> 3, r = nwg & 7;
    int xcd = nb & 7, ii = nb >> 3;
    int w = (xcd < r ? xcd * (q + 1) : r * (q + 1) + (xcd - r) * q) + ii;
    int rowBase = (w / gxc) * 128;
    int colBase = (w % gxc) * 128;

    const unsigned short* gA[2];
    const unsigned short* gB[2];
#pragma unroll
    for (int it = 0; it < 2; ++it) {
        int j = it * 256 + tid;
        int row = j >> 2, slot = j & 3;
        int ss = slot ^ ((row >> 1) & 3);  // inverse swizzle on source
        int rg = rowBase + row;
        if (rg >= NR) rg = NR - 1;  // clamp (garbage rows never written out)
        gA[it] = A + (size_t)rg * K + ss * 8;
        gB[it] = Bt + (size_t)(colBase + row) * K + ss * 8;
    }

    auto STAGE = [&](int buf, int k0) {
#pragma unroll
        for (int it = 0; it < 2; ++it) {
            unsigned short* lbase = &As[buf][(it * 256 + wave * 64) * 8];
            gload16(gA[it] + k0, lbase);
            unsigned short* lbase2 = &Bs[buf][(it * 256 + wave * 64) * 8];
            gload16(gB[it] + k0, lbase2);
        }
    };

    f32x4 acc[4][4] = {};
    int nt = K >> 5;
    STAGE(0, 0);
    __syncthreads();
    for (int t = 0; t < nt; ++t) {
        int cur = t & 1;
        if (t + 1 < nt) STAGE(cur ^ 1, (t + 1) << 5);  // issue before compute
        bf16x8 af[4], bfr[4];
#pragma unroll
        for (int m = 0; m < 4; m++) {
            int row = wr * 64 + m * 16 + r16;
            af[m] = *(const bf16x8*)&As[cur][row * 32 + (kg ^ ((row >> 1) & 3)) * 8];
        }
#pragma unroll
        for (int n = 0; n < 4; n++) {
            int row = wc * 64 + n * 16 + r16;
            bfr[n] = *(const bf16x8*)&Bs[cur][row * 32 + (kg ^ ((row >> 1) & 3)) * 8];
        }
#pragma unroll
        for (int m = 0; m < 4; m++)
#pragma unroll
            for (int n = 0; n < 4; n++)
                acc[m][n] = __builtin_amdgcn_mfma_f32_16x16x32_bf16(af[m], bfr[n], acc[m][n], 0, 0, 0);
        __syncthreads();
    }
    // ---- C write (fp8 e4m3) ----
    int crow0 = rowBase + wr * 64;
    int ccol = colBase + wc * 64 + r16;
#pragma unroll
    for (int m = 0; m < 4; m++) {
#pragma unroll
        for (int j = 0; j < 4; j++) {
            int row = crow0 + m * 16 + kg * 4 + j;
            if (row < NR) {
#pragma unroll
                for (int n = 0; n < 4; n++)
                    C8[(size_t)row * M + ccol + n * 16] = f2fp8(acc[m][n][j]);
            }
        }
    }
    // ---- fused attention-score epilogue (f32 acc, full precision) ----
    int h_blk = colBase >> 7;
    float as_[4], ad_[4];
#pragma unroll
    for (int n = 0; n < 4; n++) {
        int ch = wc * 64 + n * 16 + r16;
        as_[n] = asrc[h_blk * 128 + ch];
        ad_[n] = adst[h_blk * 128 + ch];
    }
#pragma unroll
    for (int m = 0; m < 4; m++) {
#pragma unroll
        for (int j = 0; j < 4; j++) {
            float e1 = 0.f, e2 = 0.f;
#pragma unroll
            for (int n = 0; n < 4; n++) {
                e1 += acc[m][n][j] * as_[n];
                e2 += acc[m][n][j] * ad_[n];
            }
#pragma unroll
            for (int mask = 1; mask < 16; mask <<= 1) {
                e1 += __shfl_xor(e1, mask, 64);
                e2 += __shfl_xor(e2, mask, 64);
            }
            if (r16 == 0) {
                int lr = wr * 64 + m * 16 + kg * 4 + j;
                esA[wc][lr] = e1;
                edA[wc][lr] = e2;
            }
        }
    }
    __syncthreads();
    if (tid < 128) {
        int row = rowBase + tid;
        if (row < NR) {
            es[row * H + h_blk] = esA[0][tid] + esA[1][tid];
            ed[row * H + h_blk] = edA[0][tid] + edA[1][tid];
        }
    }
}

// ---------------- fused softmax + aggregation (no-max form, fp8 gather) ----------------
template <int VEC>
__device__ inline void edge_load(const unsigned char* rp, uint2& w) {
    if constexpr (VEC == 8) {
        w = *(const uint2*)rp;
    } else {
        w.x = *(const unsigned int*)rp;
        w.y = 0;
    }
}

template <int VEC>
__device__ inline void edge_acc(float* acc, float e, const uint2& w) {
    auto p0 = __builtin_amdgcn_cvt_pk_f32_fp8(w.x, false);
    auto p1 = __builtin_amdgcn_cvt_pk_f32_fp8(w.x, true);
    acc[0] += e * p0[0]; acc[1] += e * p0[1];
    acc[2] += e * p1[0]; acc[3] += e * p1[1];
    if constexpr (VEC == 8) {
        auto p2 = __builtin_amdgcn_cvt_pk_f32_fp8(w.y, false);
        auto p3 = __builtin_amdgcn_cvt_pk_f32_fp8(w.y, true);
        acc[4] += e * p2[0]; acc[5] += e * p2[1];
        acc[6] += e * p3[0]; acc[7] += e * p3[1];
    }
}

template <int VEC, int H>  // M = 32*VEC cols; lanes 0-31 even edges, 32-63 odd edges
__global__ __launch_bounds__(256) void k_aggregate(
        const unsigned char* __restrict__ xl, const float* __restrict__ es,
        const float* __restrict__ ed, const int* __restrict__ offsets,
        const int* __restrict__ count, const unsigned short* __restrict__ ssrc,
        const float* __restrict__ bias, unsigned short* __restrict__ out) {
    const int M = 32 * VEC;
    int wid = threadIdx.x >> 6;
    int n = blockIdx.x * 4 + wid;
    if (n >= NN) return;
    int lane = threadIdx.x & 63;
    int half = lane >> 5, l32 = lane & 31;
    int c0 = l32 * VEC;
    int h = (H == 2) ? (c0 >> 7) : 0;

    float edn0, edn1 = 0.f, self0, self1 = 0.f;
    if constexpr (H == 2) {
        float2 edp = *(const float2*)&ed[n * 2];
        float2 esp = *(const float2*)&es[n * 2];
        edn0 = edp.x; edn1 = edp.y;
        self0 = __expf(leaky(esp.x + edn0));
        self1 = __expf(leaky(esp.y + edn1));
    } else {
        edn0 = ed[n];
        self0 = __expf(leaky(es[n] + edn0));
    }
    float ex_self = (H == 2 && h == 1) ? self1 : self0;

    float acc[VEC] = {};
    if (half == 0) {
        uint2 w;
        edge_load<VEC>(xl + (size_t)n * M + c0, w);
        edge_acc<VEC>(acc, ex_self, w);
    }

    // ---- single pass: cooperative score -> wave LDS, half-wave gather ----
    __shared__ int ls[4][64];
    __shared__ float le[4][H][64];
    float den0 = 0.f, den1 = 0.f;
    int s0 = offsets[n], cnte = count[n];
    for (int base = 0; base < cnte; base += 64) {
        int i = base + lane;
        int s = 0;
        float e0 = 0.f, e1 = 0.f;
        if (i < cnte) {
            s = ssrc[s0 + i];
            if constexpr (H == 2) {
                float2 esp = *(const float2*)&es[s * 2];
                e0 = __expf(leaky(esp.x + edn0)); den0 += e0;
                e1 = __expf(leaky(esp.y + edn1)); den1 += e1;
            } else {
                e0 = __expf(leaky(es[s] + edn0)); den0 += e0;
            }
        }
        ls[wid][lane] = s;
        le[wid][0][lane] = e0;
        if constexpr (H == 2) le[wid][1][lane] = e1;
        asm volatile("s_waitcnt lgkmcnt(0)" ::: "memory");
        int lim = min(64, cnte - base);
        int j = half;
        for (; j + 7 < lim; j += 8) {  // 4 independent edges in flight
            int sA = ls[wid][j], sB = ls[wid][j + 2], sC = ls[wid][j + 4], sD = ls[wid][j + 6];
            float eA = le[wid][h][j], eB = le[wid][h][j + 2];
            float eC = le[wid][h][j + 4], eD = le[wid][h][j + 6];
            uint2 wA, wB, wC, wD;
            edge_load<VEC>(xl + (size_t)sA * M + c0, wA);
            edge_load<VEC>(xl + (size_t)sB * M + c0, wB);
            edge_load<VEC>(xl + (size_t)sC * M + c0, wC);
            edge_load<VEC>(xl + (size_t)sD * M + c0, wD);
            edge_acc<VEC>(acc, eA, wA);
            edge_acc<VEC>(acc, eB, wB);
            edge_acc<VEC>(acc, eC, wC);
            edge_acc<VEC>(acc, eD, wD);
        }
        for (; j < lim; j += 2) {
            int sA = ls[wid][j];
            float eA = le[wid][h][j];
            uint2 wA;
            edge_load<VEC>(xl + (size_t)sA * M + c0, wA);
            edge_acc<VEC>(acc, eA, wA);
        }
    }

    // ---- reductions ----
#pragma unroll
    for (int off = 32; off > 0; off >>= 1) {
        den0 += __shfl_xor(den0, off, 64);
        if constexpr (H == 2) den1 += __shfl_xor(den1, off, 64);
    }
#pragma unroll
    for (int v = 0; v < VEC; v++) acc[v] += __shfl_xor(acc[v], 32, 64);

    float den = ((H == 2 && h == 1) ? den1 : den0) + ex_self + 1e-16f;
    float inv = 1.f / den;
    if (half == 0) {
        unsigned short* op = out + (size_t)n * M + c0;
        if constexpr (VEC == 8) {
            uint4 o;
            o.x = packbf(acc[0] * inv + bias[c0 + 0], acc[1] * inv + bias[c0 + 1]);
            o.y = packbf(acc[2] * inv + bias[c0 + 2], acc[3] * inv + bias[c0 + 3]);
            o.z = packbf(acc[4] * inv + bias[c0 + 4], acc[5] * inv + bias[c0 + 5]);
            o.w = packbf(acc[6] * inv + bias[c0 + 6], acc[7] * inv + bias[c0 + 7]);
            *(uint4*)op = o;
        } else {
            uint2 o;
            o.x = packbf(acc[0] * inv + bias[c0 + 0], acc[1] * inv + bias[c0 + 1]);
            o.y = packbf(acc[2] * inv + bias[c0 + 2], acc[3] * inv + bias[c0 + 3]);
            *(uint2*)op = o;
        }
    }
}

// ---------------- edge sort by dst (counting sort) ----------------
// rank[e] = this edge's order among edges with the same dst (free from the count atomic)
__global__ void k_count(const int* __restrict__ dst, int* __restrict__ count,
                        int* __restrict__ rank) {
    int e = blockIdx.x * blockDim.x + threadIdx.x;
    if (e < EE) rank[e] = atomicAdd(&count[dst[e]], 1);
}

__global__ void k_scan_local(const int* __restrict__ in, int* __restrict__ out_excl,
                             int* __restrict__ bsums, int n) {
    __shared__ int s[256];
    int tid = threadIdx.x;
    int i = blockIdx.x * 256 + tid;
    int v = (i < n) ? in[i] : 0;
    s[tid] = v;
    __syncthreads();
    for (int off = 1; off < 256; off <<= 1) {
        int t_ = (tid >= off) ? s[tid - off] : 0;
        __syncthreads();
        s[tid] += t_;
        __syncthreads();
    }
    if (i < n) out_excl[i] = s[tid] - v;
    if (tid == 255) bsums[blockIdx.x] = s[255];
}

__global__ void k_scan_sums(int* __restrict__ b, int n) {
    __shared__ int s[256];
    int tid = threadIdx.x;
    int v = (tid < n) ? b[tid] : 0;
    s[tid] = v;
    __syncthreads();
    for (int off = 1; off < 256; off <<= 1) {
        int t_ = (tid >= off) ? s[tid - off] : 0;
        __syncthreads();
        s[tid] += t_;
        __syncthreads();
    }
    if (tid < n) b[tid] = s[tid] - v;
}

__global__ void k_scan_add(int* __restrict__ out_excl, const int* __restrict__ bsums, int n) {
    int i = blockIdx.x * 256 + threadIdx.x;
    if (i < n) out_excl[i] += bsums[blockIdx.x];
}

// atomic-free scatter: position fully determined by offsets + precomputed rank
__global__ void k_scatter(const int* __restrict__ src, const int* __restrict__ dst,
                          const int* __restrict__ offsets, const int* __restrict__ rank,
                          unsigned short* __restrict__ ssrc) {
    int e = blockIdx.x * blockDim.x + threadIdx.x;
    if (e >= EE) return;
    ssrc[offsets[dst[e]] + rank[e]] = (unsigned short)src[e];
}

// ---------------- batch norm: 256-block partial stats (f32, no atomics) ----------------
__global__ __launch_bounds__(256) void k_bn_stats(const unsigned short* __restrict__ h,
                                                  float* __restrict__ part) {
    int tid = threadIdx.x;
    int bid = blockIdx.x;      // 256 blocks
    int c0 = (tid & 31) * 8;   // 8 cols per thread
    int rg = tid >> 5;         // 8 row groups
    float s[8] = {}, s2[8] = {};
    for (int r = bid * 8 + rg; r < NN; r += 2048) {
        uint4 v = *(const uint4*)(h + (size_t)r * 256 + c0);
        float f;
        f = bflo(v.x); s[0] += f; s2[0] += f * f;
        f = bfhi(v.x); s[1] += f; s2[1] += f * f;
        f = bflo(v.y); s[2] += f; s2[2] += f * f;
        f = bfhi(v.y); s[3] += f; s2[3] += f * f;
        f = bflo(v.z); s[4] += f; s2[4] += f * f;
        f = bfhi(v.z); s[5] += f; s2[5] += f * f;
        f = bflo(v.w); s[6] += f; s2[6] += f * f;
        f = bfhi(v.w); s[7] += f; s2[7] += f * f;
    }
    __shared__ float sb[8][256];
#pragma unroll
    for (int v = 0; v < 8; v++) sb[rg][c0 + v] = s[v];
    __syncthreads();
    float tot = 0.f;
#pragma unroll
    for (int g = 0; g < 8; g++) tot += sb[g][tid];
    part[bid * 512 + tid] = tot;
    __syncthreads();
#pragma unroll
    for (int v = 0; v < 8; v++) sb[rg][c0 + v] = s2[v];
    __syncthreads();
    tot = 0.f;
#pragma unroll
    for (int g = 0; g < 8; g++) tot += sb[g][tid];
    part[bid * 512 + 256 + tid] = tot;
}

__global__ void k_bn_finalize(const float* __restrict__ part, const float* __restrict__ g,
                              const float* __restrict__ be, float* __restrict__ scale,
                              float* __restrict__ shift) {
    int t = threadIdx.x;  // 256
    float s = 0.f, s2 = 0.f;
    for (int b = 0; b < 256; b++) {
        s += part[b * 512 + t];
        s2 += part[b * 512 + 256 + t];
    }
    float mu = s / (float)NN;
    float var = s2 / (float)NN - mu * mu;
    float sc = g[t] * rsqrtf(var + BN_EPS);
    scale[t] = sc;
    shift[t] = be[t] - mu * sc;
}

__global__ void k_bn_apply(unsigned short* __restrict__ h, const float* __restrict__ scale,
                           const float* __restrict__ shift) {
    int i = blockIdx.x * blockDim.x + threadIdx.x;
    int stride = gridDim.x * blockDim.x;
    int total = NN * 256 / 8;
    uint4* h4 = (uint4*)h;
    for (; i < total; i += stride) {
        uint4 v = h4[i];
        int t = (i * 8) & 255;
        float f0 = fmaxf(bflo(v.x) * scale[t + 0] + shift[t + 0], 0.f);
        float f1 = fmaxf(bfhi(v.x) * scale[t + 1] + shift[t + 1], 0.f);
        float f2 = fmaxf(bflo(v.y) * scale[t + 2] + shift[t + 2], 0.f);
        float f3 = fmaxf(bfhi(v.y) * scale[t + 3] + shift[t + 3], 0.f);
        float f4 = fmaxf(bflo(v.z) * scale[t + 4] + shift[t + 4], 0.f);
        float f5 = fmaxf(bfhi(v.z) * scale[t + 5] + shift[t + 5], 0.f);
        float f6 = fmaxf(bflo(v.w) * scale[t + 6] + shift[t + 6], 0.f);
        float f7 = fmaxf(bfhi(v.w) * scale[t + 7] + shift[t + 7], 0.f);
        v.x = packbf(f0, f1);
        v.y = packbf(f2, f3);
        v.z = packbf(f4, f5);
        v.w = packbf(f6, f7);
        h4[i] = v;
    }
}

// ---------------- pooling + final linear ----------------
#define POOL_ROWS 128
__global__ void k_pool(const unsigned short* __restrict__ h3, const int* __restrict__ batch,
                       float* __restrict__ pooled, int* __restrict__ cnt) {
    int t = threadIdx.x;  // 128
    int r0 = blockIdx.x * POOL_ROWS;
    if (r0 >= NN) return;
    int rend = min(r0 + POOL_ROWS, NN);
    float acc = 0.f;
    int c_acc = 0;
    int g_cur = batch[r0];
    for (int r = r0; r < rend; r++) {
        int g = batch[r];
        if (g != g_cur) {
            atomicAdd(&pooled[g_cur * 128 + t], acc);
            if (t == 0) atomicAdd(&cnt[g_cur], c_acc);
            acc = 0.f;
            c_acc = 0;
            g_cur = g;
        }
        acc += bf2f(h3[(size_t)r * 128 + t]);
        c_acc++;
    }
    atomicAdd(&pooled[g_cur * 128 + t], acc);
    if (t == 0) atomicAdd(&cnt[g_cur], c_acc);
}

__global__ void k_final(const float* __restrict__ pooled, const int* __restrict__ cnt,
                        const float* __restrict__ Wlin, const float* __restrict__ blin,
                        float* __restrict__ out) {
    int g = blockIdx.x;   // 64
    int o = threadIdx.x;  // 64
    float c = (float)max(cnt[g], 1);
    float acc = 0.f;
    for (int k = 0; k < 128; k++) acc += pooled[g * 128 + k] * Wlin[k * 64 + o];
    out[g * 64 + o] = acc / c + blin[o];
}

// ---------------- host ----------------
extern "C" void kernel_launch(void* const* d_in, const int* in_sizes, int n_in,
                              void* d_out, int out_size, void* d_ws, size_t ws_size,
                              hipStream_t stream) {
    const float* x = (const float*)d_in[0];
    const int* ei = (const int*)d_in[1];
    const int* batch = (const int*)d_in[2];
    const float* W1 = (const float*)d_in[3];
    const float* as1 = (const float*)d_in[4];
    const float* ad1 = (const float*)d_in[5];
    const float* b1 = (const float*)d_in[6];
    const float* g1 = (const float*)d_in[7];
    const float* be1 = (const float*)d_in[8];
    const float* W2 = (const float*)d_in[9];
    const float* as2 = (const float*)d_in[10];
    const float* ad2 = (const float*)d_in[11];
    const float* b2 = (const float*)d_in[12];
    const float* g2 = (const float*)d_in[13];
    const float* be2 = (const float*)d_in[14];
    const float* W3 = (const float*)d_in[15];
    const float* as3 = (const float*)d_in[16];
    const float* ad3 = (const float*)d_in[17];
    const float* b3 = (const float*)d_in[18];
    const float* Wlin = (const float*)d_in[19];
    const float* blin = (const float*)d_in[20];
    float* out = (float*)d_out;

    const int* src = ei;
    const int* dst = ei + EE;

    char* ws = (char*)d_ws;
    size_t off = 0;
    auto alloc = [&](size_t bytes) -> void* {
        void* p = (void*)(ws + off);
        off = (off + bytes + 255) & ~(size_t)255;
        return p;
    };
    unsigned short* xb = (unsigned short*)alloc((size_t)NN * 512 * 2);
    unsigned char* xl = (unsigned char*)alloc((size_t)NN * 256);
    unsigned short* hbuf = (unsigned short*)alloc((size_t)NN * 256 * 2);
    unsigned short* Wt1 = (unsigned short*)alloc((size_t)256 * 512 * 2);
    unsigned short* Wt2 = (unsigned short*)alloc((size_t)256 * 256 * 2);
    unsigned short* Wt3 = (unsigned short*)alloc((size_t)128 * 256 * 2);
    float* es = (float*)alloc((size_t)NN * 2 * 4);
    float* ed = (float*)alloc((size_t)NN * 2 * 4);
    int* count = (int*)alloc((size_t)NN * 4);
    int* offsets = (int*)alloc((size_t)NN * 4);
    int* rank = (int*)alloc((size_t)EE * 4);
    unsigned short* ssrc = (unsigned short*)alloc((size_t)EE * 2);
    int* bsums = (int*)alloc(256 * 4);
    float* bnpart = (float*)alloc((size_t)256 * 512 * 4);
    float* bnscale = (float*)alloc(256 * 4);
    float* bnshift = (float*)alloc(256 * 4);
    float* pooled = (float*)alloc(64 * 128 * 4);  // cnt directly follows (aligned)
    int* cnt = (int*)alloc(64 * 4);

    const int EB = (EE + 255) / 256;  // 3125
    const int NB = (NN + 255) / 256;  // 196
    const int AGB = (NN + 3) / 4;     // 12500
    const int NRB = (NN + 127) / 128; // 391

    // ---- one-time input prep (convert + transposes + zero count/pooled/cnt) ----
    k_prep<<<2048, 256, 0, stream>>>(x, xb, W1, W2, W3, Wt1, Wt2, Wt3, count, pooled);

    // ---- sort edges by dst (once; graph shared across layers) ----
    k_count<<<EB, 256, 0, stream>>>(dst, count, rank);
    k_scan_local<<<NB, 256, 0, stream>>>(count, offsets, bsums, NN);
    k_scan_sums<<<1, 256, 0, stream>>>(bsums, NB);
    k_scan_add<<<NB, 256, 0, stream>>>(offsets, bsums, NN);
    k_scatter<<<EB, 256, 0, stream>>>(src, dst, offsets, rank, ssrc);

    auto bn_relu = [&](unsigned short* h, const float* g_, const float* be_) {
        k_bn_stats<<<256, 256, 0, stream>>>(h, bnpart);
        k_bn_finalize<<<1, 256, 0, stream>>>(bnpart, g_, be_, bnscale, bnshift);
        k_bn_apply<<<1024, 256, 0, stream>>>(h, bnscale, bnshift);
    };

    // ---- layer 1: 512 -> [2,128] concat 256 ----
    k_gemm_mfma<<<2 * NRB, 256, 0, stream>>>(xb, Wt1, xl, as1, ad1, es, ed, NN, 512, 256, 2, 2);
    k_aggregate<8, 2><<<AGB, 256, 0, stream>>>(xl, es, ed, offsets, count, ssrc, b1, hbuf);
    bn_relu(hbuf, g1, be1);

    // ---- layer 2: 256 -> 256 ----
    k_gemm_mfma<<<2 * NRB, 256, 0, stream>>>(hbuf, Wt2, xl, as2, ad2, es, ed, NN, 256, 256, 2, 2);
    k_aggregate<8, 2><<<AGB, 256, 0, stream>>>(xl, es, ed, offsets, count, ssrc, b2, hbuf);
    bn_relu(hbuf, g2, be2);

    // ---- layer 3: 256 -> 128, 1 head ----
    k_gemm_mfma<<<NRB, 256, 0, stream>>>(hbuf, Wt3, xl, as3, ad3, es, ed, NN, 256, 128, 1, 1);
    k_aggregate<4, 1><<<AGB, 256, 0, stream>>>(xl, es, ed, offsets, count, ssrc, b3, hbuf);

    // ---- global mean pool + final linear ----
    k_pool<<<(NN + POOL_ROWS - 1) / POOL_ROWS, 128, 0, stream>>>(hbuf, batch, pooled, cnt);
    k_final<<<GG, 64, 0, stream>>>(pooled, cnt, Wlin, blin, out);
}